// Round 1
// baseline (295.491 us; speedup 1.0000x reference)
//
#include <hip/hip_runtime.h>
#include <math.h>

namespace {

constexpr int NX  = 512;    // data points
constexpr int M   = 514;    // basis functions = NX + 2 (cubic, clamped knots)
constexpr int NE  = 8192;   // eval points
constexpr int NBC = 256;    // batch*channels = 8*32

// workspace layout in floats
constexpr int WS_BX = 0;                  // bx  [NX*4]
constexpr int WS_LB = WS_BX + NX * 4;     // Lb  [(M+3)*4]  (rd, l1, l2, l3), 3 zero pad rows
constexpr int WS_B  = WS_LB + (M + 3) * 4; // B  [M*NBC]    Btz -> y -> coef (in place)

// knot vector: t[0..2]=-1, t[3..514]=x[0..511], t[515..517]=+1
__device__ __forceinline__ float knotf(int j) {
    int c = j - 3;
    c = c < 0 ? 0 : (c > NX - 1 ? NX - 1 : c);
    return -1.0f + 2.0f * (float)c / 511.0f;
}

// de Boor: span j with t[j] <= x < t[j+1], j in [3, 513].
// Returns N[0..3] = B_{j-3..j}(x). No zero denominators for j in [3,513].
__device__ __forceinline__ void deboor3(float x, int j, float N[4]) {
    N[0] = 1.0f; N[1] = 0.0f; N[2] = 0.0f; N[3] = 0.0f;
#pragma unroll
    for (int d = 1; d <= 3; ++d) {
        float saved = 0.0f;
#pragma unroll
        for (int r = 0; r < 3; ++r) {
            if (r < d) {
                float tr = knotf(j + r + 1);
                float tl = knotf(j + r + 1 - d);
                float temp = N[r] / (tr - tl);
                N[r] = saved + (tr - x) * temp;
                saved = (x - tl) * temp;
            }
        }
        N[d] = saved;
    }
}

// ---------------------------------------------------------------------------
// Kernel 1: data basis (512x4 sparse rows), banded BtB (in LDS), serial
// banded Cholesky -> L band (rd = 1/diag, l1, l2, l3) into ws.
// ---------------------------------------------------------------------------
__global__ __launch_bounds__(512) void prep_kernel(float* __restrict__ ws) {
    __shared__ float bx_s[NX * 4];
    __shared__ float A_s[M * 4];   // A[i][q] = BtB[i][i-q], q=0..3
    const int tid = threadIdx.x;

    // phase A: basis at data points. off(n) = min(n, 510), span j = off+3.
    if (tid < NX) {
        const int n = tid;
        const int off = n < NX - 1 ? n : NX - 2;
        const float x = -1.0f + 2.0f * (float)n / 511.0f;
        float N[4];
        deboor3(x, off + 3, N);
#pragma unroll
        for (int r = 0; r < 4; ++r) {
            bx_s[n * 4 + r] = N[r];
            ws[WS_BX + n * 4 + r] = N[r];
        }
    }
    __syncthreads();

    // phase B: banded BtB + smoothing on diagonal
    for (int i = tid; i < M; i += 512) {
        float a0 = 0.f, a1 = 0.f, a2 = 0.f, a3 = 0.f;
        const int n0 = i - 3 < 0 ? 0 : i - 3;
        const int n1 = i + 1 > NX - 1 ? NX - 1 : i + 1;
        for (int n = n0; n <= n1; ++n) {
            const int off = n < NX - 1 ? n : NX - 2;
            const int ri = i - off;
            if (ri < 0 || ri > 3) continue;
            const float bi = bx_s[n * 4 + ri];
            a0 += bi * bx_s[n * 4 + ri];
            if (ri >= 1) a1 += bi * bx_s[n * 4 + ri - 1];
            if (ri >= 2) a2 += bi * bx_s[n * 4 + ri - 2];
            if (ri >= 3) a3 += bi * bx_s[n * 4 + ri - 3];
        }
        A_s[i * 4 + 0] = a0 + 1e-3f;
        A_s[i * 4 + 1] = a1;
        A_s[i * 4 + 2] = a2;
        A_s[i * 4 + 3] = a3;
    }
    __syncthreads();

    // phase C: serial banded Cholesky, rolling registers for prev 3 rows.
    if (tid == 0) {
        float rd1 = 0.f, l1p = 0.f, l2p = 0.f;  // row i-1: rd, l1, l2
        float rd2 = 0.f, l1pp = 0.f;            // row i-2: rd, l1
        float rd3 = 0.f;                        // row i-3: rd
        for (int i = 0; i < M; ++i) {
            const float a0 = A_s[i * 4 + 0];
            const float a1 = A_s[i * 4 + 1];
            const float a2 = A_s[i * 4 + 2];
            const float a3 = A_s[i * 4 + 3];
            const float l3 = a3 * rd3;
            const float l2 = (a2 - l3 * l1pp) * rd2;
            const float l1 = (a1 - l3 * l2p - l2 * l1p) * rd1;
            const float s  = a0 - l3 * l3 - l2 * l2 - l1 * l1;
            const float rd = 1.0f / sqrtf(s);
            ws[WS_LB + i * 4 + 0] = rd;
            ws[WS_LB + i * 4 + 1] = l1;
            ws[WS_LB + i * 4 + 2] = l2;
            ws[WS_LB + i * 4 + 3] = l3;
            rd3 = rd2; rd2 = rd1; rd1 = rd;
            l1pp = l1p; l1p = l1; l2p = l2;
        }
        // zero pad rows M..M+2 so backward substitution needs no guards
#pragma unroll
        for (int i = M; i < M + 3; ++i)
#pragma unroll
            for (int q = 0; q < 4; ++q) ws[WS_LB + i * 4 + q] = 0.0f;
    }
}

// ---------------------------------------------------------------------------
// Kernel 2: Btz[i][bc] = sum_n bx[n][i-off(n)] * Z[bc][n]  (coalesced writes)
// ---------------------------------------------------------------------------
__global__ __launch_bounds__(256) void btz_kernel(const float* __restrict__ Z,
                                                  float* __restrict__ ws) {
    const float* bx = ws + WS_BX;
    float* B = ws + WS_B;
    const int i = blockIdx.x;    // 0..513
    const int bc = threadIdx.x;  // 0..255
    const int n0 = i - 3 < 0 ? 0 : i - 3;
    const int n1 = i + 1 > NX - 1 ? NX - 1 : i + 1;
    float acc = 0.0f;
    for (int n = n0; n <= n1; ++n) {
        const int off = n < NX - 1 ? n : NX - 2;
        const int r = i - off;
        if (r >= 0 && r <= 3) acc += bx[n * 4 + r] * Z[bc * NX + n];
    }
    B[i * NBC + bc] = acc;
}

// ---------------------------------------------------------------------------
// Kernel 3: forward + backward substitution, in place in B. 256 RHS.
// ---------------------------------------------------------------------------
__global__ __launch_bounds__(64) void solve_kernel(float* __restrict__ ws) {
    const float* Lb = ws + WS_LB;
    float* B = ws + WS_B;
    const int bc = blockIdx.x * 64 + threadIdx.x;
    float y1 = 0.f, y2 = 0.f, y3 = 0.f;
    for (int i = 0; i < M; ++i) {
        const float rd = Lb[i * 4 + 0];
        const float l1 = Lb[i * 4 + 1];
        const float l2 = Lb[i * 4 + 2];
        const float l3 = Lb[i * 4 + 3];
        const float v = (B[i * NBC + bc] - l1 * y1 - l2 * y2 - l3 * y3) * rd;
        B[i * NBC + bc] = v;
        y3 = y2; y2 = y1; y1 = v;
    }
    float c1 = 0.f, c2 = 0.f, c3 = 0.f;
    for (int i = M - 1; i >= 0; --i) {
        const float e1 = Lb[(i + 1) * 4 + 1];
        const float e2 = Lb[(i + 2) * 4 + 2];
        const float e3 = Lb[(i + 3) * 4 + 3];
        const float rd = Lb[i * 4 + 0];
        const float c = (B[i * NBC + bc] - e1 * c1 - e2 * c2 - e3 * c3) * rd;
        B[i * NBC + bc] = c;
        c3 = c2; c2 = c1; c1 = c;
    }
}

// ---------------------------------------------------------------------------
// Kernel 4: evaluate. block -> (bc, 256-chunk of n); inline de Boor per point.
// out[bc*8192 + n] = sum_r N[r] * coef[off+r][bc]
// ---------------------------------------------------------------------------
__global__ __launch_bounds__(256) void eval_kernel(const float* __restrict__ ws,
                                                   float* __restrict__ out) {
    const float* B = ws + WS_B;
    const int bc = blockIdx.x >> 5;                         // 0..255
    const int n = ((blockIdx.x & 31) << 8) | threadIdx.x;   // 0..8191
    const float xe = -1.0f + 2.0f * (float)n / 8191.0f;
    int off = (int)((xe + 1.0f) * 255.5f);                  // 255.5 = 1/h, h = 2/511
    off = off < 0 ? 0 : (off > NX - 2 ? NX - 2 : off);
    float N[4];
    deboor3(xe, off + 3, N);
    const float r = N[0] * B[(off + 0) * NBC + bc]
                  + N[1] * B[(off + 1) * NBC + bc]
                  + N[2] * B[(off + 2) * NBC + bc]
                  + N[3] * B[(off + 3) * NBC + bc];
    out[bc * NE + n] = r;
}

}  // namespace

extern "C" void kernel_launch(void* const* d_in, const int* in_sizes, int n_in,
                              void* d_out, int out_size, void* d_ws, size_t ws_size,
                              hipStream_t stream) {
    const float* Z = (const float*)d_in[0];
    float* out = (float*)d_out;
    float* ws = (float*)d_ws;

    hipLaunchKernelGGL(prep_kernel, dim3(1), dim3(512), 0, stream, ws);
    hipLaunchKernelGGL(btz_kernel, dim3(M), dim3(NBC), 0, stream, Z, ws);
    hipLaunchKernelGGL(solve_kernel, dim3(4), dim3(64), 0, stream, ws);
    hipLaunchKernelGGL(eval_kernel, dim3(NE / 256 * NBC), dim3(256), 0, stream, ws, out);
}

// Round 2
// 132.820 us; speedup vs baseline: 2.2247x; 2.2247x over previous
//
#include <hip/hip_runtime.h>
#include <math.h>

namespace {

constexpr int NX  = 512;    // data points
constexpr int M   = 514;    // basis functions = NX + 2 (cubic, clamped knots)
constexpr int NE  = 8192;   // eval points
constexpr int NBC = 256;    // batch*channels = 8*32

// workspace layout in floats
constexpr int WS_BX = 0;                  // bx  [NX*4]
constexpr int WS_LB = WS_BX + NX * 4;     // Lb  [(M+3)*4]  (rd, l1, l2, l3), 3 zero pad rows
constexpr int WS_B  = WS_LB + (M + 3) * 4; // B  [M*NBC]    Btz -> y -> coef (in place)

// knot vector: t[0..2]=-1, t[3..514]=x[0..511], t[515..517]=+1
__device__ __forceinline__ float knotf(int j) {
    int c = j - 3;
    c = c < 0 ? 0 : (c > NX - 1 ? NX - 1 : c);
    return -1.0f + 2.0f * (float)c / 511.0f;
}

// de Boor: span j with t[j] <= x < t[j+1], j in [3, 513].
__device__ __forceinline__ void deboor3(float x, int j, float N[4]) {
    N[0] = 1.0f; N[1] = 0.0f; N[2] = 0.0f; N[3] = 0.0f;
#pragma unroll
    for (int d = 1; d <= 3; ++d) {
        float saved = 0.0f;
#pragma unroll
        for (int r = 0; r < 3; ++r) {
            if (r < d) {
                float tr = knotf(j + r + 1);
                float tl = knotf(j + r + 1 - d);
                float temp = N[r] / (tr - tl);
                N[r] = saved + (tr - x) * temp;
                saved = (x - tl) * temp;
            }
        }
        N[d] = saved;
    }
}

// ---------------------------------------------------------------------------
// Kernel 1: data basis, banded BtB (LDS), serial banded Cholesky -> ws.
// ---------------------------------------------------------------------------
__global__ __launch_bounds__(512) void prep_kernel(float* __restrict__ ws) {
    __shared__ float bx_s[NX * 4];
    __shared__ float A_s[M * 4];   // A[i][q] = BtB[i][i-q], q=0..3
    const int tid = threadIdx.x;

    if (tid < NX) {
        const int n = tid;
        const int off = n < NX - 1 ? n : NX - 2;
        const float x = -1.0f + 2.0f * (float)n / 511.0f;
        float N[4];
        deboor3(x, off + 3, N);
#pragma unroll
        for (int r = 0; r < 4; ++r) {
            bx_s[n * 4 + r] = N[r];
            ws[WS_BX + n * 4 + r] = N[r];
        }
    }
    __syncthreads();

    for (int i = tid; i < M; i += 512) {
        float a0 = 0.f, a1 = 0.f, a2 = 0.f, a3 = 0.f;
        const int n0 = i - 3 < 0 ? 0 : i - 3;
        const int n1 = i + 1 > NX - 1 ? NX - 1 : i + 1;
        for (int n = n0; n <= n1; ++n) {
            const int off = n < NX - 1 ? n : NX - 2;
            const int ri = i - off;
            if (ri < 0 || ri > 3) continue;
            const float bi = bx_s[n * 4 + ri];
            a0 += bi * bx_s[n * 4 + ri];
            if (ri >= 1) a1 += bi * bx_s[n * 4 + ri - 1];
            if (ri >= 2) a2 += bi * bx_s[n * 4 + ri - 2];
            if (ri >= 3) a3 += bi * bx_s[n * 4 + ri - 3];
        }
        A_s[i * 4 + 0] = a0 + 1e-3f;
        A_s[i * 4 + 1] = a1;
        A_s[i * 4 + 2] = a2;
        A_s[i * 4 + 3] = a3;
    }
    __syncthreads();

    if (tid == 0) {
        float rd1 = 0.f, l1p = 0.f, l2p = 0.f;
        float rd2 = 0.f, l1pp = 0.f;
        float rd3 = 0.f;
        for (int i = 0; i < M; ++i) {
            const float a0 = A_s[i * 4 + 0];
            const float a1 = A_s[i * 4 + 1];
            const float a2 = A_s[i * 4 + 2];
            const float a3 = A_s[i * 4 + 3];
            const float l3 = a3 * rd3;
            const float l2 = (a2 - l3 * l1pp) * rd2;
            const float l1 = (a1 - l3 * l2p - l2 * l1p) * rd1;
            const float s  = a0 - l3 * l3 - l2 * l2 - l1 * l1;
            const float rd = 1.0f / sqrtf(s);
            ws[WS_LB + i * 4 + 0] = rd;
            ws[WS_LB + i * 4 + 1] = l1;
            ws[WS_LB + i * 4 + 2] = l2;
            ws[WS_LB + i * 4 + 3] = l3;
            rd3 = rd2; rd2 = rd1; rd1 = rd;
            l1pp = l1p; l1p = l1; l2p = l2;
        }
#pragma unroll
        for (int i = M; i < M + 3; ++i)
#pragma unroll
            for (int q = 0; q < 4; ++q) ws[WS_LB + i * 4 + q] = 0.0f;
    }
}

// ---------------------------------------------------------------------------
// Kernel 2: Btz[i][bc] = sum_n bx[n][i-off(n)] * Z[bc][n]
// ---------------------------------------------------------------------------
__global__ __launch_bounds__(256) void btz_kernel(const float* __restrict__ Z,
                                                  float* __restrict__ ws) {
    const float* bx = ws + WS_BX;
    float* B = ws + WS_B;
    const int i = blockIdx.x;
    const int bc = threadIdx.x;
    const int n0 = i - 3 < 0 ? 0 : i - 3;
    const int n1 = i + 1 > NX - 1 ? NX - 1 : i + 1;
    float acc = 0.0f;
    for (int n = n0; n <= n1; ++n) {
        const int off = n < NX - 1 ? n : NX - 2;
        const int r = i - off;
        if (r >= 0 && r <= 3) acc += bx[n * 4 + r] * Z[bc * NX + n];
    }
    B[i * NBC + bc] = acc;
}

// ---------------------------------------------------------------------------
// Kernel 3: fwd + bwd substitution, in place. Lb staged in LDS; B loads
// software-pipelined through a depth-16 register ring (all static indices).
// ---------------------------------------------------------------------------
constexpr int PF = 16;           // prefetch depth
constexpr int NFULL = 512;       // 32 chunks of 16; tail = 2 rows

__global__ __launch_bounds__(64) void solve_kernel(float* __restrict__ ws) {
    __shared__ float Lb_s[(M + 3) * 4];
    const int tid = threadIdx.x;
    for (int idx = tid; idx < (M + 3) * 4; idx += 64) Lb_s[idx] = ws[WS_LB + idx];
    __syncthreads();

    float* B = ws + WS_B;
    const int bc = blockIdx.x * 64 + tid;
    const float4* Lb4 = (const float4*)Lb_s;

    float buf[PF];

    // ---- forward: rows 0..513 ----
#pragma unroll
    for (int d = 0; d < PF; ++d) buf[d] = B[d * NBC + bc];
    float y1 = 0.f, y2 = 0.f, y3 = 0.f;
    for (int ii = 0; ii < NFULL; ii += PF) {
#pragma unroll
        for (int j = 0; j < PF; ++j) {
            const int i = ii + j;
            const float4 l = Lb4[i];   // broadcast ds_read_b128
            const float v = (buf[j] - l.y * y1 - l.z * y2 - l.w * y3) * l.x;
            B[i * NBC + bc] = v;
            y3 = y2; y2 = y1; y1 = v;
            int ip = i + PF; ip = ip < M ? ip : M - 1;   // clamp (unused slots)
            buf[j] = B[ip * NBC + bc];
        }
    }
#pragma unroll
    for (int j = 0; j < 2; ++j) {    // rows 512, 513 from buf[0], buf[1]
        const int i = NFULL + j;
        const float4 l = Lb4[i];
        const float v = (buf[j] - l.y * y1 - l.z * y2 - l.w * y3) * l.x;
        B[i * NBC + bc] = v;
        y3 = y2; y2 = y1; y1 = v;
    }

    // ---- backward: rows 513..0 ----
#pragma unroll
    for (int d = 0; d < PF; ++d) buf[d] = B[(M - 1 - d) * NBC + bc];
    float c1 = 0.f, c2 = 0.f, c3 = 0.f;
    for (int ii = 0; ii < NFULL; ii += PF) {
#pragma unroll
        for (int j = 0; j < PF; ++j) {
            const int i = M - 1 - (ii + j);
            const float e1 = Lb_s[(i + 1) * 4 + 1];
            const float e2 = Lb_s[(i + 2) * 4 + 2];
            const float e3 = Lb_s[(i + 3) * 4 + 3];
            const float rd = Lb_s[i * 4 + 0];
            const float c = (buf[j] - e1 * c1 - e2 * c2 - e3 * c3) * rd;
            B[i * NBC + bc] = c;
            c3 = c2; c2 = c1; c1 = c;
            int ip = i - PF; ip = ip > 0 ? ip : 0;       // clamp (unused slots)
            buf[j] = B[ip * NBC + bc];
        }
    }
#pragma unroll
    for (int j = 0; j < 2; ++j) {    // rows 1, 0 from buf[0], buf[1]
        const int i = 1 - j;
        const float e1 = Lb_s[(i + 1) * 4 + 1];
        const float e2 = Lb_s[(i + 2) * 4 + 2];
        const float e3 = Lb_s[(i + 3) * 4 + 3];
        const float rd = Lb_s[i * 4 + 0];
        const float c = (buf[j] - e1 * c1 - e2 * c2 - e3 * c3) * rd;
        B[i * NBC + bc] = c;
        c3 = c2; c2 = c1; c1 = c;
    }
}

// ---------------------------------------------------------------------------
// Kernel 4: evaluate at 8192 points, coalesced 8 MB write.
// ---------------------------------------------------------------------------
__global__ __launch_bounds__(256) void eval_kernel(const float* __restrict__ ws,
                                                   float* __restrict__ out) {
    const float* B = ws + WS_B;
    const int bc = blockIdx.x >> 5;
    const int n = ((blockIdx.x & 31) << 8) | threadIdx.x;
    const float xe = -1.0f + 2.0f * (float)n / 8191.0f;
    int off = (int)((xe + 1.0f) * 255.5f);
    off = off < 0 ? 0 : (off > NX - 2 ? NX - 2 : off);
    float N[4];
    deboor3(xe, off + 3, N);
    const float r = N[0] * B[(off + 0) * NBC + bc]
                  + N[1] * B[(off + 1) * NBC + bc]
                  + N[2] * B[(off + 2) * NBC + bc]
                  + N[3] * B[(off + 3) * NBC + bc];
    out[bc * NE + n] = r;
}

}  // namespace

extern "C" void kernel_launch(void* const* d_in, const int* in_sizes, int n_in,
                              void* d_out, int out_size, void* d_ws, size_t ws_size,
                              hipStream_t stream) {
    const float* Z = (const float*)d_in[0];
    float* out = (float*)d_out;
    float* ws = (float*)d_ws;

    hipLaunchKernelGGL(prep_kernel, dim3(1), dim3(512), 0, stream, ws);
    hipLaunchKernelGGL(btz_kernel, dim3(M), dim3(NBC), 0, stream, Z, ws);
    hipLaunchKernelGGL(solve_kernel, dim3(4), dim3(64), 0, stream, ws);
    hipLaunchKernelGGL(eval_kernel, dim3(NE / 256 * NBC), dim3(256), 0, stream, ws, out);
}

// Round 3
// 74.324 us; speedup vs baseline: 3.9757x; 1.7870x over previous
//
#include <hip/hip_runtime.h>
#include <math.h>

namespace {

constexpr int NX  = 512;    // data points
constexpr int M   = 514;    // basis functions = NX + 2 (cubic, clamped knots)
constexpr int NE  = 8192;   // eval points
constexpr int NBC = 256;    // batch*channels = 8*32
constexpr int NCONV = 128;  // rows of exact serial Cholesky before converged fill

// workspace layout in floats
constexpr int WS_BX = 0;                   // bx  [NX*4]
constexpr int WS_LB = WS_BX + NX * 4;      // Lb  [(M+3)*4]  (rd, l1, l2, l3), 3 zero pad rows
constexpr int WS_B  = WS_LB + (M + 3) * 4; // B   [M*NBC]    Btz -> y -> coef (in place)

// knot vector: t[0..2]=-1, t[3..514]=x[0..511], t[515..517]=+1
__device__ __forceinline__ float knotf(int j) {
    int c = j - 3;
    c = c < 0 ? 0 : (c > NX - 1 ? NX - 1 : c);
    return -1.0f + 2.0f * (float)c / 511.0f;
}

// de Boor: span j with t[j] <= x < t[j+1], j in [3, 513].
__device__ __forceinline__ void deboor3(float x, int j, float N[4]) {
    N[0] = 1.0f; N[1] = 0.0f; N[2] = 0.0f; N[3] = 0.0f;
#pragma unroll
    for (int d = 1; d <= 3; ++d) {
        float saved = 0.0f;
#pragma unroll
        for (int r = 0; r < 3; ++r) {
            if (r < d) {
                float tr = knotf(j + r + 1);
                float tl = knotf(j + r + 1 - d);
                float temp = N[r] / (tr - tl);
                N[r] = saved + (tr - x) * temp;
                saved = (x - tl) * temp;
            }
        }
        N[d] = saved;
    }
}

// ---------------------------------------------------------------------------
// Kernel 1: data basis, banded BtB (LDS), converged-stencil banded Cholesky.
// Interior of BtB is Toeplitz (rows 7..506) -> recursion hits an fp32 fixed
// point; run exact rows 0..NCONV-1, broadcast-fill middle, finish last 7 rows.
// ---------------------------------------------------------------------------
__global__ __launch_bounds__(512) void prep_kernel(float* __restrict__ ws) {
    __shared__ float bx_s[NX * 4];
    __shared__ float4 A_s4[M];     // A[i] = (BtB[i][i]+S, [i][i-1], [i][i-2], [i][i-3])
    __shared__ float4 conv_s;      // converged (rd, l1, l2, l3)
    const int tid = threadIdx.x;

    // phase A: basis at data points
    if (tid < NX) {
        const int n = tid;
        const int off = n < NX - 1 ? n : NX - 2;
        const float x = -1.0f + 2.0f * (float)n / 511.0f;
        float N[4];
        deboor3(x, off + 3, N);
#pragma unroll
        for (int r = 0; r < 4; ++r) {
            bx_s[n * 4 + r] = N[r];
            ws[WS_BX + n * 4 + r] = N[r];
        }
    }
    __syncthreads();

    // phase B: banded BtB + smoothing on diagonal
    for (int i = tid; i < M; i += 512) {
        float a0 = 0.f, a1 = 0.f, a2 = 0.f, a3 = 0.f;
        const int n0 = i - 3 < 0 ? 0 : i - 3;
        const int n1 = i + 1 > NX - 1 ? NX - 1 : i + 1;
        for (int n = n0; n <= n1; ++n) {
            const int off = n < NX - 1 ? n : NX - 2;
            const int ri = i - off;
            if (ri < 0 || ri > 3) continue;
            const float bi = bx_s[n * 4 + ri];
            a0 += bi * bx_s[n * 4 + ri];
            if (ri >= 1) a1 += bi * bx_s[n * 4 + ri - 1];
            if (ri >= 2) a2 += bi * bx_s[n * 4 + ri - 2];
            if (ri >= 3) a3 += bi * bx_s[n * 4 + ri - 3];
        }
        A_s4[i] = make_float4(a0 + 1e-3f, a1, a2, a3);
    }
    __syncthreads();

    float4* Lb4g = (float4*)(ws + WS_LB);

    // phase C: serial head + converged fill + serial tail (single lane for
    // the serial parts, parallel coalesced fill for the Toeplitz middle).
    if (tid == 0) {
        float rd1 = 0.f, l1p = 0.f, l2p = 0.f;
        float rd2 = 0.f, l1pp = 0.f;
        float rd3 = 0.f;
        float l3s = 0.f;
#pragma unroll 4
        for (int i = 0; i < NCONV; ++i) {
            const float4 a = A_s4[i];
            const float l3 = a.w * rd3;
            const float l2 = (a.z - l3 * l1pp) * rd2;
            const float l1 = (a.y - l3 * l2p - l2 * l1p) * rd1;
            const float s  = a.x - l3 * l3 - l2 * l2 - l1 * l1;
            const float rd = __builtin_amdgcn_rsqf(s);
            Lb4g[i] = make_float4(rd, l1, l2, l3);
            rd3 = rd2; rd2 = rd1; rd1 = rd;
            l1pp = l1p; l1p = l1; l2p = l2;
            l3s = l3;
        }
        // converged row (fp32 fixed point by row NCONV-1)
        conv_s = make_float4(rd1, l1p, l2p, l3s);
        // set rolling state as if rows M-8, M-9, M-10 were all converged
        rd3 = rd2 = rd1;
        l1pp = l1p;
        // l2p already converged
#pragma unroll
        for (int i = M - 7; i < M; ++i) {
            const float4 a = A_s4[i];
            const float l3 = a.w * rd3;
            const float l2 = (a.z - l3 * l1pp) * rd2;
            const float l1 = (a.y - l3 * l2p - l2 * l1p) * rd1;
            const float s  = a.x - l3 * l3 - l2 * l2 - l1 * l1;
            const float rd = __builtin_amdgcn_rsqf(s);
            Lb4g[i] = make_float4(rd, l1, l2, l3);
            rd3 = rd2; rd2 = rd1; rd1 = rd;
            l1pp = l1p; l1p = l1; l2p = l2;
        }
        // zero pad rows M..M+2 (backward substitution reads past the end)
#pragma unroll
        for (int i = M; i < M + 3; ++i) Lb4g[i] = make_float4(0.f, 0.f, 0.f, 0.f);
    }
    __syncthreads();

    // parallel coalesced fill of the Toeplitz middle rows
    const float4 cv = conv_s;
    for (int i = NCONV + tid; i <= M - 8; i += 512) Lb4g[i] = cv;
}

// ---------------------------------------------------------------------------
// Kernel 2: Btz[i][bc] = sum_n bx[n][i-off(n)] * Z[bc][n]
// ---------------------------------------------------------------------------
__global__ __launch_bounds__(256) void btz_kernel(const float* __restrict__ Z,
                                                  float* __restrict__ ws) {
    const float* bx = ws + WS_BX;
    float* B = ws + WS_B;
    const int i = blockIdx.x;
    const int bc = threadIdx.x;
    const int n0 = i - 3 < 0 ? 0 : i - 3;
    const int n1 = i + 1 > NX - 1 ? NX - 1 : i + 1;
    float acc = 0.0f;
    for (int n = n0; n <= n1; ++n) {
        const int off = n < NX - 1 ? n : NX - 2;
        const int r = i - off;
        if (r >= 0 && r <= 3) acc += bx[n * 4 + r] * Z[bc * NX + n];
    }
    B[i * NBC + bc] = acc;
}

// ---------------------------------------------------------------------------
// Kernel 3: fwd + bwd substitution, in place. Lb staged in LDS; B loads
// software-pipelined through a depth-16 register ring (all static indices).
// ---------------------------------------------------------------------------
constexpr int PF = 16;           // prefetch depth
constexpr int NFULL = 512;       // 32 chunks of 16; tail = 2 rows

__global__ __launch_bounds__(64) void solve_kernel(float* __restrict__ ws) {
    __shared__ float Lb_s[(M + 3) * 4];
    const int tid = threadIdx.x;
    for (int idx = tid; idx < (M + 3) * 4; idx += 64) Lb_s[idx] = ws[WS_LB + idx];
    __syncthreads();

    float* B = ws + WS_B;
    const int bc = blockIdx.x * 64 + tid;
    const float4* Lb4 = (const float4*)Lb_s;

    float buf[PF];

    // ---- forward: rows 0..513 ----
#pragma unroll
    for (int d = 0; d < PF; ++d) buf[d] = B[d * NBC + bc];
    float y1 = 0.f, y2 = 0.f, y3 = 0.f;
    for (int ii = 0; ii < NFULL; ii += PF) {
#pragma unroll
        for (int j = 0; j < PF; ++j) {
            const int i = ii + j;
            const float4 l = Lb4[i];   // broadcast ds_read_b128
            const float v = (buf[j] - l.y * y1 - l.z * y2 - l.w * y3) * l.x;
            B[i * NBC + bc] = v;
            y3 = y2; y2 = y1; y1 = v;
            int ip = i + PF; ip = ip < M ? ip : M - 1;   // clamp (unused slots)
            buf[j] = B[ip * NBC + bc];
        }
    }
#pragma unroll
    for (int j = 0; j < 2; ++j) {    // rows 512, 513 from buf[0], buf[1]
        const int i = NFULL + j;
        const float4 l = Lb4[i];
        const float v = (buf[j] - l.y * y1 - l.z * y2 - l.w * y3) * l.x;
        B[i * NBC + bc] = v;
        y3 = y2; y2 = y1; y1 = v;
    }

    // ---- backward: rows 513..0 ----
#pragma unroll
    for (int d = 0; d < PF; ++d) buf[d] = B[(M - 1 - d) * NBC + bc];
    float c1 = 0.f, c2 = 0.f, c3 = 0.f;
    for (int ii = 0; ii < NFULL; ii += PF) {
#pragma unroll
        for (int j = 0; j < PF; ++j) {
            const int i = M - 1 - (ii + j);
            const float e1 = Lb_s[(i + 1) * 4 + 1];
            const float e2 = Lb_s[(i + 2) * 4 + 2];
            const float e3 = Lb_s[(i + 3) * 4 + 3];
            const float rd = Lb_s[i * 4 + 0];
            const float c = (buf[j] - e1 * c1 - e2 * c2 - e3 * c3) * rd;
            B[i * NBC + bc] = c;
            c3 = c2; c2 = c1; c1 = c;
            int ip = i - PF; ip = ip > 0 ? ip : 0;       // clamp (unused slots)
            buf[j] = B[ip * NBC + bc];
        }
    }
#pragma unroll
    for (int j = 0; j < 2; ++j) {    // rows 1, 0 from buf[0], buf[1]
        const int i = 1 - j;
        const float e1 = Lb_s[(i + 1) * 4 + 1];
        const float e2 = Lb_s[(i + 2) * 4 + 2];
        const float e3 = Lb_s[(i + 3) * 4 + 3];
        const float rd = Lb_s[i * 4 + 0];
        const float c = (buf[j] - e1 * c1 - e2 * c2 - e3 * c3) * rd;
        B[i * NBC + bc] = c;
        c3 = c2; c2 = c1; c1 = c;
    }
}

// ---------------------------------------------------------------------------
// Kernel 4: evaluate at 8192 points, coalesced 8 MB write.
// ---------------------------------------------------------------------------
__global__ __launch_bounds__(256) void eval_kernel(const float* __restrict__ ws,
                                                   float* __restrict__ out) {
    const float* B = ws + WS_B;
    const int bc = blockIdx.x >> 5;
    const int n = ((blockIdx.x & 31) << 8) | threadIdx.x;
    const float xe = -1.0f + 2.0f * (float)n / 8191.0f;
    int off = (int)((xe + 1.0f) * 255.5f);
    off = off < 0 ? 0 : (off > NX - 2 ? NX - 2 : off);
    float N[4];
    deboor3(xe, off + 3, N);
    const float r = N[0] * B[(off + 0) * NBC + bc]
                  + N[1] * B[(off + 1) * NBC + bc]
                  + N[2] * B[(off + 2) * NBC + bc]
                  + N[3] * B[(off + 3) * NBC + bc];
    out[bc * NE + n] = r;
}

}  // namespace

extern "C" void kernel_launch(void* const* d_in, const int* in_sizes, int n_in,
                              void* d_out, int out_size, void* d_ws, size_t ws_size,
                              hipStream_t stream) {
    const float* Z = (const float*)d_in[0];
    float* out = (float*)d_out;
    float* ws = (float*)d_ws;

    hipLaunchKernelGGL(prep_kernel, dim3(1), dim3(512), 0, stream, ws);
    hipLaunchKernelGGL(btz_kernel, dim3(M), dim3(NBC), 0, stream, Z, ws);
    hipLaunchKernelGGL(solve_kernel, dim3(4), dim3(64), 0, stream, ws);
    hipLaunchKernelGGL(eval_kernel, dim3(NE / 256 * NBC), dim3(256), 0, stream, ws, out);
}

// Round 4
// 60.696 us; speedup vs baseline: 4.8684x; 1.2245x over previous
//
#include <hip/hip_runtime.h>
#include <math.h>

namespace {

constexpr int NX  = 512;    // data points
constexpr int M   = 514;    // basis functions = NX + 2 (cubic, clamped knots)
constexpr int NE  = 8192;   // eval points
constexpr int NBC = 256;    // batch*channels = 8*32
constexpr int NCONV = 128;  // rows of exact serial Cholesky before converged fill

// segmented substitution
constexpr int SEG  = 64;    // stored rows per segment
constexpr int WARM = 64;    // warm-up rows (decay 0.268^64 -> exact in fp32)
constexpr int NSEG = 8;     // 8 segments; last covers 66 rows (512,513 tail)
constexpr int PF2  = 32;    // prefetch ring depth

// workspace layout in floats
constexpr int WS_BX = 0;                    // bx  [NX*4]
constexpr int WS_LB = WS_BX + NX * 4;       // Lb  [(M+3)*4] (rd,l1,l2,l3), 3 zero pad rows
constexpr int WS_B  = WS_LB + (M + 3) * 4;  // B   [M*NBC]  Btz -> coef (backward overwrites)
constexpr int WS_Y  = WS_B + M * NBC;       // Y   [M*NBC]  forward-substitution output

// knot vector: t[0..2]=-1, t[3..514]=x[0..511], t[515..517]=+1
__device__ __forceinline__ float knotf(int j) {
    int c = j - 3;
    c = c < 0 ? 0 : (c > NX - 1 ? NX - 1 : c);
    return -1.0f + 2.0f * (float)c / 511.0f;
}

// de Boor: span j with t[j] <= x < t[j+1], j in [3, 513].
__device__ __forceinline__ void deboor3(float x, int j, float N[4]) {
    N[0] = 1.0f; N[1] = 0.0f; N[2] = 0.0f; N[3] = 0.0f;
#pragma unroll
    for (int d = 1; d <= 3; ++d) {
        float saved = 0.0f;
#pragma unroll
        for (int r = 0; r < 3; ++r) {
            if (r < d) {
                float tr = knotf(j + r + 1);
                float tl = knotf(j + r + 1 - d);
                float temp = N[r] / (tr - tl);
                N[r] = saved + (tr - x) * temp;
                saved = (x - tl) * temp;
            }
        }
        N[d] = saved;
    }
}

// ---------------------------------------------------------------------------
// Kernel 1: data basis, banded BtB (LDS), converged-stencil banded Cholesky.
// ---------------------------------------------------------------------------
__global__ __launch_bounds__(512) void prep_kernel(float* __restrict__ ws) {
    __shared__ float bx_s[NX * 4];
    __shared__ float4 A_s4[M];
    __shared__ float4 conv_s;
    const int tid = threadIdx.x;

    if (tid < NX) {
        const int n = tid;
        const int off = n < NX - 1 ? n : NX - 2;
        const float x = -1.0f + 2.0f * (float)n / 511.0f;
        float N[4];
        deboor3(x, off + 3, N);
#pragma unroll
        for (int r = 0; r < 4; ++r) {
            bx_s[n * 4 + r] = N[r];
            ws[WS_BX + n * 4 + r] = N[r];
        }
    }
    __syncthreads();

    for (int i = tid; i < M; i += 512) {
        float a0 = 0.f, a1 = 0.f, a2 = 0.f, a3 = 0.f;
        const int n0 = i - 3 < 0 ? 0 : i - 3;
        const int n1 = i + 1 > NX - 1 ? NX - 1 : i + 1;
        for (int n = n0; n <= n1; ++n) {
            const int off = n < NX - 1 ? n : NX - 2;
            const int ri = i - off;
            if (ri < 0 || ri > 3) continue;
            const float bi = bx_s[n * 4 + ri];
            a0 += bi * bx_s[n * 4 + ri];
            if (ri >= 1) a1 += bi * bx_s[n * 4 + ri - 1];
            if (ri >= 2) a2 += bi * bx_s[n * 4 + ri - 2];
            if (ri >= 3) a3 += bi * bx_s[n * 4 + ri - 3];
        }
        A_s4[i] = make_float4(a0 + 1e-3f, a1, a2, a3);
    }
    __syncthreads();

    float4* Lb4g = (float4*)(ws + WS_LB);

    if (tid == 0) {
        float rd1 = 0.f, l1p = 0.f, l2p = 0.f;
        float rd2 = 0.f, l1pp = 0.f;
        float rd3 = 0.f;
        float l3s = 0.f;
#pragma unroll 4
        for (int i = 0; i < NCONV; ++i) {
            const float4 a = A_s4[i];
            const float l3 = a.w * rd3;
            const float l2 = (a.z - l3 * l1pp) * rd2;
            const float l1 = (a.y - l3 * l2p - l2 * l1p) * rd1;
            const float s  = a.x - l3 * l3 - l2 * l2 - l1 * l1;
            const float rd = __builtin_amdgcn_rsqf(s);
            Lb4g[i] = make_float4(rd, l1, l2, l3);
            rd3 = rd2; rd2 = rd1; rd1 = rd;
            l1pp = l1p; l1p = l1; l2p = l2;
            l3s = l3;
        }
        conv_s = make_float4(rd1, l1p, l2p, l3s);
        rd3 = rd2 = rd1;
        l1pp = l1p;
#pragma unroll
        for (int i = M - 7; i < M; ++i) {
            const float4 a = A_s4[i];
            const float l3 = a.w * rd3;
            const float l2 = (a.z - l3 * l1pp) * rd2;
            const float l1 = (a.y - l3 * l2p - l2 * l1p) * rd1;
            const float s  = a.x - l3 * l3 - l2 * l2 - l1 * l1;
            const float rd = __builtin_amdgcn_rsqf(s);
            Lb4g[i] = make_float4(rd, l1, l2, l3);
            rd3 = rd2; rd2 = rd1; rd1 = rd;
            l1pp = l1p; l1p = l1; l2p = l2;
        }
#pragma unroll
        for (int i = M; i < M + 3; ++i) Lb4g[i] = make_float4(0.f, 0.f, 0.f, 0.f);
    }
    __syncthreads();

    const float4 cv = conv_s;
    for (int i = NCONV + tid; i <= M - 8; i += 512) Lb4g[i] = cv;
}

// ---------------------------------------------------------------------------
// Kernel 2: Btz[i][bc] = sum_n bx[n][i-off(n)] * Z[bc][n]
// ---------------------------------------------------------------------------
__global__ __launch_bounds__(256) void btz_kernel(const float* __restrict__ Z,
                                                  float* __restrict__ ws) {
    const float* bx = ws + WS_BX;
    float* B = ws + WS_B;
    const int i = blockIdx.x;
    const int bc = threadIdx.x;
    const int n0 = i - 3 < 0 ? 0 : i - 3;
    const int n1 = i + 1 > NX - 1 ? NX - 1 : i + 1;
    float acc = 0.0f;
    for (int n = n0; n <= n1; ++n) {
        const int off = n < NX - 1 ? n : NX - 2;
        const int r = i - off;
        if (r >= 0 && r <= 3) acc += bx[n * 4 + r] * Z[bc * NX + n];
    }
    B[i * NBC + bc] = acc;
}

// ---------------------------------------------------------------------------
// Kernel 3a: segmented forward substitution. Block = segment (8 blocks),
// 256 lanes = 256 RHS. 64 warm-up rows (zero state; recurrence error decays
// as 0.268^t -> exact by row `start`), 64 stored rows (+2 tail in seg 7).
// Reads B, writes Y.
// ---------------------------------------------------------------------------
__global__ __launch_bounds__(256) void solve_f(float* __restrict__ ws) {
    __shared__ float4 Lb4s[M + 3];
    const int tid = threadIdx.x;
    {
        const float4* src = (const float4*)(ws + WS_LB);
        for (int i = tid; i < M + 3; i += 256) Lb4s[i] = src[i];
    }
    __syncthreads();

    const float* B = ws + WS_B;
    float* Y = ws + WS_Y;
    const int seg = blockIdx.x;
    const int bc = tid;
    const int start = seg * SEG;
    const int w0 = start - WARM;

    float buf[PF2];
#pragma unroll
    for (int d = 0; d < PF2; ++d) {
        const int ip = w0 + d;
        float t = 0.f;
        if (ip >= 0) t = B[ip * NBC + bc];
        buf[d] = t;
    }

    float y1 = 0.f, y2 = 0.f, y3 = 0.f;
    for (int c = 0; c < (WARM + SEG) / PF2; ++c) {
#pragma unroll
        for (int j = 0; j < PF2; ++j) {
            const int i = w0 + c * PF2 + j;
            const int il = i < 0 ? 0 : i;
            const float4 l = Lb4s[il];
            const float v = (buf[j] - l.z * y2 - l.w * y3 - l.y * y1) * l.x;
            if (i >= start) Y[i * NBC + bc] = v;
            y3 = y2; y2 = y1; y1 = v;
            const int ip = i + PF2;
            float t = 0.f;
            if (ip >= 0 && ip < M) t = B[ip * NBC + bc];
            buf[j] = t;
        }
    }
    if (seg == NSEG - 1) {
#pragma unroll
        for (int j = 0; j < 2; ++j) {
            const int i = NSEG * SEG + j;   // 512, 513
            const float4 l = Lb4s[i];
            const float v = (buf[j] - l.z * y2 - l.w * y3 - l.y * y1) * l.x;
            Y[i * NBC + bc] = v;
            y3 = y2; y2 = y1; y1 = v;
        }
    }
}

// ---------------------------------------------------------------------------
// Kernel 3b: segmented backward substitution. Reads Y, writes coef over B.
// Segment 7 starts exactly at row 513 (warm-up rows >= M read 0).
// ---------------------------------------------------------------------------
__global__ __launch_bounds__(256) void solve_b(float* __restrict__ ws) {
    __shared__ float4 Lb4s[M + 3];
    const int tid = threadIdx.x;
    {
        const float4* src = (const float4*)(ws + WS_LB);
        for (int i = tid; i < M + 3; i += 256) Lb4s[i] = src[i];
    }
    __syncthreads();

    const float* Y = ws + WS_Y;
    float* C = ws + WS_B;   // coef overwrites B
    const int seg = blockIdx.x;
    const int bc = tid;
    const int start = seg * SEG;
    const int end = (seg == NSEG - 1) ? M : start + SEG;
    const int e = end + WARM - 1;   // topmost row of descent

    float buf[PF2];
#pragma unroll
    for (int d = 0; d < PF2; ++d) {
        const int ip = e - d;
        float t = 0.f;
        if (ip < M) t = Y[ip * NBC + bc];
        buf[d] = t;
    }

    float c1 = 0.f, c2 = 0.f, c3 = 0.f;
    for (int cc = 0; cc < (WARM + SEG) / PF2; ++cc) {
#pragma unroll
        for (int j = 0; j < PF2; ++j) {
            const int i = e - (cc * PF2 + j);
            const int i0 = i < M - 1 ? i : M - 1;
            const int i1 = i + 1 < M + 2 ? i + 1 : M + 2;
            const int i2 = i + 2 < M + 2 ? i + 2 : M + 2;
            const int i3 = i + 3 < M + 2 ? i + 3 : M + 2;
            const float rd = Lb4s[i0].x;
            const float e1 = Lb4s[i1].y;
            const float e2 = Lb4s[i2].z;
            const float e3 = Lb4s[i3].w;
            const float v = (buf[j] - e2 * c2 - e3 * c3 - e1 * c1) * rd;
            if (i < end) C[i * NBC + bc] = v;
            c3 = c2; c2 = c1; c1 = v;
            const int ip = i - PF2;
            float t = 0.f;
            if (ip >= 0 && ip < M) t = Y[ip * NBC + bc];
            buf[j] = t;
        }
    }
    if (seg == NSEG - 1) {
#pragma unroll
        for (int j = 0; j < 2; ++j) {
            const int i = 449 - j;          // 449, 448
            const float rd = Lb4s[i].x;
            const float e1 = Lb4s[i + 1].y;
            const float e2 = Lb4s[i + 2].z;
            const float e3 = Lb4s[i + 3].w;
            const float v = (buf[j] - e2 * c2 - e3 * c3 - e1 * c1) * rd;
            C[i * NBC + bc] = v;
            c3 = c2; c2 = c1; c1 = v;
        }
    }
}

// ---------------------------------------------------------------------------
// Kernel 4: evaluate at 8192 points, coalesced 8 MB write.
// ---------------------------------------------------------------------------
__global__ __launch_bounds__(256) void eval_kernel(const float* __restrict__ ws,
                                                   float* __restrict__ out) {
    const float* B = ws + WS_B;
    const int bc = blockIdx.x >> 5;
    const int n = ((blockIdx.x & 31) << 8) | threadIdx.x;
    const float xe = -1.0f + 2.0f * (float)n / 8191.0f;
    int off = (int)((xe + 1.0f) * 255.5f);
    off = off < 0 ? 0 : (off > NX - 2 ? NX - 2 : off);
    float N[4];
    deboor3(xe, off + 3, N);
    const float r = N[0] * B[(off + 0) * NBC + bc]
                  + N[1] * B[(off + 1) * NBC + bc]
                  + N[2] * B[(off + 2) * NBC + bc]
                  + N[3] * B[(off + 3) * NBC + bc];
    out[bc * NE + n] = r;
}

}  // namespace

extern "C" void kernel_launch(void* const* d_in, const int* in_sizes, int n_in,
                              void* d_out, int out_size, void* d_ws, size_t ws_size,
                              hipStream_t stream) {
    const float* Z = (const float*)d_in[0];
    float* out = (float*)d_out;
    float* ws = (float*)d_ws;

    hipLaunchKernelGGL(prep_kernel, dim3(1), dim3(512), 0, stream, ws);
    hipLaunchKernelGGL(btz_kernel, dim3(M), dim3(NBC), 0, stream, Z, ws);
    hipLaunchKernelGGL(solve_f, dim3(NSEG), dim3(NBC), 0, stream, ws);
    hipLaunchKernelGGL(solve_b, dim3(NSEG), dim3(NBC), 0, stream, ws);
    hipLaunchKernelGGL(eval_kernel, dim3(NE / 256 * NBC), dim3(256), 0, stream, ws, out);
}

// Round 5
// 53.242 us; speedup vs baseline: 5.5500x; 1.1400x over previous
//
#include <hip/hip_runtime.h>
#include <math.h>

namespace {

constexpr int NX  = 512;    // data points
constexpr int M   = 514;    // basis functions
constexpr int NE  = 8192;   // eval points
constexpr int NBC = 256;    // batch*channels
constexpr int WARM = 32;    // warm-up rows (decay ~0.268^32 ~ 5e-19 -> fp32-exact)

constexpr int NBLK  = 32;   // solve blocks
constexpr int PPB   = NE / NBLK;   // 256 eval points per solve block
constexpr int NCOLF = 88;   // staged Z columns per block (fixed)
constexpr int STRIDE = 93;  // LDS row stride (floats); 93%32=29, coprime -> 2-way max

// ---------------------------------------------------------------------------
// Compile-time tables: basis weights and banded Cholesky factor (double math).
// ---------------------------------------------------------------------------
constexpr double dknot(int j) {
    int c = j - 3;
    c = c < 0 ? 0 : (c > NX - 1 ? NX - 1 : c);
    return -1.0 + 2.0 * (double)c / 511.0;
}

constexpr double csqrt(double x) {
    double r = x > 1.0 ? x : 1.0;
    for (int k = 0; k < 50; ++k) r = 0.5 * (r + x / r);
    return r;
}

struct Tables {
    alignas(16) float lb[M + 3][4];  // rd=1/diag, l1, l2, l3 (3 zero pad rows)
    alignas(16) float w4[M][4];      // w4[i][r] = weight of Z[i-r] in Btz[i]
    float we[4];                     // weight of Z[511] in Btz[510+q]
};

constexpr Tables make_tables() {
    Tables T{};
    // basis at data points (de Boor, double)
    double bx[NX][4] = {};
    for (int n = 0; n < NX; ++n) {
        const int off = n < NX - 1 ? n : NX - 2;
        const double x = -1.0 + 2.0 * (double)n / 511.0;
        double N[4] = {1.0, 0.0, 0.0, 0.0};
        for (int d = 1; d <= 3; ++d) {
            double saved = 0.0;
            for (int r = 0; r < d; ++r) {
                const double tr = dknot(off + 3 + r + 1);
                const double tl = dknot(off + 3 + r + 1 - d);
                const double temp = N[r] / (tr - tl);
                N[r] = saved + (tr - x) * temp;
                saved = (x - tl) * temp;
            }
            N[d] = saved;
        }
        for (int r = 0; r < 4; ++r) bx[n][r] = N[r];
    }
    // banded BtB + smoothing
    double A[M][4] = {};
    for (int i = 0; i < M; ++i) {
        double a0 = 1e-3, a1 = 0.0, a2 = 0.0, a3 = 0.0;
        const int nlo = i - 3 < 0 ? 0 : i - 3;
        const int nhi = i + 1 > NX - 1 ? NX - 1 : i + 1;
        for (int n = nlo; n <= nhi; ++n) {
            const int off = n < NX - 1 ? n : NX - 2;
            const int ri = i - off;
            if (ri < 0 || ri > 3) continue;
            const double bi = bx[n][ri];
            a0 += bi * bx[n][ri];
            if (ri >= 1) a1 += bi * bx[n][ri - 1];
            if (ri >= 2) a2 += bi * bx[n][ri - 2];
            if (ri >= 3) a3 += bi * bx[n][ri - 3];
        }
        A[i][0] = a0; A[i][1] = a1; A[i][2] = a2; A[i][3] = a3;
    }
    // banded Cholesky (rolling registers)
    {
        double rd1 = 0.0, l1p = 0.0, l2p = 0.0, rd2 = 0.0, l1pp = 0.0, rd3 = 0.0;
        for (int i = 0; i < M; ++i) {
            const double l3 = A[i][3] * rd3;
            const double l2 = (A[i][2] - l3 * l1pp) * rd2;
            const double l1 = (A[i][1] - l3 * l2p - l2 * l1p) * rd1;
            const double s  = A[i][0] - l3 * l3 - l2 * l2 - l1 * l1;
            const double rd = 1.0 / csqrt(s);
            T.lb[i][0] = (float)rd; T.lb[i][1] = (float)l1;
            T.lb[i][2] = (float)l2; T.lb[i][3] = (float)l3;
            rd3 = rd2; rd2 = rd1; rd1 = rd;
            l1pp = l1p; l1p = l1; l2p = l2;
        }
        // pad rows M..M+2 stay zero
    }
    // Btz weights: Btz[i] = sum_r w4[i][r]*Z[i-r] (+ we[i-510]*Z[511] for i>=510)
    for (int i = 0; i < M; ++i)
        for (int r = 0; r < 4; ++r) {
            const int n = i - r;
            T.w4[i][r] = (n >= 0 && n <= NX - 2) ? (float)bx[n][r] : 0.0f;
        }
    for (int q = 0; q < 4; ++q) T.we[q] = (float)bx[NX - 1][q];
    return T;
}

__constant__ Tables TBL = make_tables();

// interval index of eval point n (same fp32 path everywhere -> consistent)
__device__ __forceinline__ int offf(int n) {
    const float xe = -1.0f + 2.0f * (float)n / 8191.0f;
    int off = (int)((xe + 1.0f) * 255.5f);
    return off < 0 ? 0 : (off > NX - 2 ? NX - 2 : off);
}

// runtime fp32 de Boor for eval points
__device__ __forceinline__ float knotf(int j) {
    int c = j - 3;
    c = c < 0 ? 0 : (c > NX - 1 ? NX - 1 : c);
    return -1.0f + 2.0f * (float)c / 511.0f;
}

__device__ __forceinline__ void deboor3(float x, int j, float N[4]) {
    N[0] = 1.0f; N[1] = 0.0f; N[2] = 0.0f; N[3] = 0.0f;
#pragma unroll
    for (int d = 1; d <= 3; ++d) {
        float saved = 0.0f;
#pragma unroll
        for (int r = 0; r < 3; ++r) {
            if (r < d) {
                const float tr = knotf(j + r + 1);
                const float tl = knotf(j + r + 1 - d);
                const float temp = N[r] / (tr - tl);
                N[r] = saved + (tr - x) * temp;
                saved = (x - tl) * temp;
            }
        }
        N[d] = saved;
    }
}

// ---------------------------------------------------------------------------
// Kernel 1: fused Btz + forward + backward substitution, per-block segment.
// Each block re-derives its owned coef rows independently (warm-up recurrences
// converge to fp32-exact within 32 rows). Lane = one RHS (bc); all row data
// lane-private in LDS -> no barriers after staging.
// LDS slot map (per bc row of stride 93): col j lives at slot j-n0 = j-i0+3;
// row i (Btz -> y -> coef, in place) lives at slot i-i0. Writing row i kills
// col i-3, which is exactly dead.
// ---------------------------------------------------------------------------
__global__ __launch_bounds__(256) void solve_fused(const float* __restrict__ Z,
                                                   float* __restrict__ coef) {
    __shared__ float Bs[256 * STRIDE];
    const int tid = threadIdx.x;
    const int b = blockIdx.x;

    // geometry (uniform)
    const int nf = b * PPB;
    const int r_lo = offf(nf);
    const int r_hi = offf(nf + PPB - 1) + 3;
    const int own_lo = r_lo;  // offf(0) == 0 for b == 0
    const int own_hi = (b == NBLK - 1) ? M - 1 : offf(nf + PPB) - 1;
    int i0 = r_lo - WARM; i0 = i0 < 0 ? 0 : i0;
    int i_end = r_hi + WARM; i_end = i_end > M - 1 ? M - 1 : i_end;
    const int n0 = i0 - 3;

    // stage Z columns [n0, n0+88) coalesced into LDS
    for (int e = tid; e < 256 * NCOLF; e += 256) {
        const int bcq = e / NCOLF;           // compile-time divisor
        const int jq = e - bcq * NCOLF;
        const int j = n0 + jq;
        float v = 0.0f;
        if (j >= 0 && j < NX) v = Z[bcq * NX + j];
        Bs[bcq * STRIDE + jq] = v;
    }
    __syncthreads();

    const int bc = tid;
    float* Brow = Bs + bc * STRIDE;
    const int s511 = NX - 1 - n0;
    const float z511 = (s511 >= 0 && s511 < NCOLF) ? Brow[s511] : 0.0f;

    // ---- forward: y_i = (Btz_i - l1*y1 - l2*y2 - l3*y3) * rd ----
    const int NR = i_end - i0 + 1;
    float y1 = 0.f, y2 = 0.f, y3 = 0.f;
    for (int ri = 0; ri < NR; ri += 8) {
        float zb[11];
#pragma unroll
        for (int m = 0; m < 11; ++m) zb[m] = Brow[ri + m];   // slots <= 90 < 93
#pragma unroll
        for (int k = 0; k < 8; ++k) {
            const int i = i0 + ri + k;
            const int it = i < M ? i : M - 1;
            const float4 w = *(const float4*)TBL.w4[it];
            const float4 l = *(const float4*)TBL.lb[it];
            float btz = w.x * zb[k + 3] + w.y * zb[k + 2] + w.z * zb[k + 1] + w.w * zb[k];
            if (i >= NX - 2 + 2) {           // i >= 510: Z[511] tap
                int q = i - 510; q = q < 0 ? 0 : (q > 3 ? 3 : q);
                btz += TBL.we[q] * z511;
            }
            const float y = (btz - l.y * y1 - l.z * y2 - l.w * y3) * l.x;
            if (ri + k < NR) Brow[ri + k] = y;
            y3 = y2; y2 = y1; y1 = y;
        }
    }

    // ---- backward: c_i = (y_i - lb[i+1].l1*c1 - lb[i+2].l2*c2 - lb[i+3].l3*c3) * lb[i].rd
    const int NRb = i_end - own_lo + 1;
    float c1 = 0.f, c2 = 0.f, c3 = 0.f;
    for (int ri = 0; ri < NRb; ri += 8) {
        float zb[8];
#pragma unroll
        for (int m = 0; m < 8; ++m) {
            int s = i_end - i0 - ri - m;
            zb[m] = Brow[s < 0 ? 0 : s];
        }
#pragma unroll
        for (int k = 0; k < 8; ++k) {
            const int i = i_end - ri - k;
            const int it = i < 0 ? 0 : i;
            const float rd = TBL.lb[it][0];
            const float e1 = TBL.lb[it + 1][1];
            const float e2 = TBL.lb[it + 2][2];
            const float e3 = TBL.lb[it + 3][3];
            const float c = (zb[k] - e1 * c1 - e2 * c2 - e3 * c3) * rd;
            if (ri + k < NRb) Brow[i - i0] = c;
            c3 = c2; c2 = c1; c1 = c;
        }
    }

    // ---- write owned coef rows (disjoint across blocks, coalesced per row)
    for (int i = own_lo; i <= own_hi; ++i)
        coef[i * NBC + bc] = Brow[i - i0];
}

// ---------------------------------------------------------------------------
// Kernel 2: evaluate. 4 points/thread, float4 coalesced stores.
// ---------------------------------------------------------------------------
__device__ __forceinline__ float evalpt(const float* __restrict__ coef, int n, int bc) {
    const float xe = -1.0f + 2.0f * (float)n / 8191.0f;
    int off = (int)((xe + 1.0f) * 255.5f);
    off = off < 0 ? 0 : (off > NX - 2 ? NX - 2 : off);
    float N[4];
    deboor3(xe, off + 3, N);
    return N[0] * coef[(off + 0) * NBC + bc]
         + N[1] * coef[(off + 1) * NBC + bc]
         + N[2] * coef[(off + 2) * NBC + bc]
         + N[3] * coef[(off + 3) * NBC + bc];
}

__global__ __launch_bounds__(256) void eval_kernel(const float* __restrict__ coef,
                                                   float* __restrict__ out) {
    const int bc = blockIdx.x >> 3;                       // 0..255
    const int n0q = ((blockIdx.x & 7) << 10) | (threadIdx.x << 2);
    float4 r;
    r.x = evalpt(coef, n0q + 0, bc);
    r.y = evalpt(coef, n0q + 1, bc);
    r.z = evalpt(coef, n0q + 2, bc);
    r.w = evalpt(coef, n0q + 3, bc);
    *(float4*)(out + bc * NE + n0q) = r;
}

}  // namespace

extern "C" void kernel_launch(void* const* d_in, const int* in_sizes, int n_in,
                              void* d_out, int out_size, void* d_ws, size_t ws_size,
                              hipStream_t stream) {
    const float* Z = (const float*)d_in[0];
    float* out = (float*)d_out;
    float* coef = (float*)d_ws;    // [M * NBC] floats

    hipLaunchKernelGGL(solve_fused, dim3(NBLK), dim3(256), 0, stream, Z, coef);
    hipLaunchKernelGGL(eval_kernel, dim3(2048), dim3(256), 0, stream, coef, out);
}

// Round 6
// 38.001 us; speedup vs baseline: 7.7758x; 1.4010x over previous
//
#include <hip/hip_runtime.h>
#include <math.h>

namespace {

constexpr int NX  = 512;    // data points
constexpr int M   = 514;    // basis functions
constexpr int NE  = 8192;   // eval points
constexpr int NBC = 256;    // batch*channels
constexpr int WARM = 32;    // warm-up rows (decay ~0.268^32 -> fp32-exact)

constexpr int NBLK = 32;    // solve blocks (one 16-coef-row segment each)
constexpr int PPB  = NE / NBLK;
constexpr int YST  = 57;    // LDS y-strip stride (odd -> conflict-free)

// ---------------------------------------------------------------------------
// Compile-time tables: basis weights and banded Cholesky factor (double math).
// ---------------------------------------------------------------------------
constexpr double dknot(int j) {
    int c = j - 3;
    c = c < 0 ? 0 : (c > NX - 1 ? NX - 1 : c);
    return -1.0 + 2.0 * (double)c / 511.0;
}

constexpr double csqrt(double x) {
    double r = x > 1.0 ? x : 1.0;
    for (int k = 0; k < 50; ++k) r = 0.5 * (r + x / r);
    return r;
}

struct Tables {
    alignas(16) float lb[M + 3][4];  // rd=1/diag, l1, l2, l3 (3 zero pad rows)
    alignas(16) float w4[M][4];      // w4[i][r] = weight of Z[i-r] in Btz[i] (0 if OOR)
    float we[4];                     // weight of Z[511] in Btz[510+q]
};

constexpr Tables make_tables() {
    Tables T{};
    double bx[NX][4] = {};
    for (int n = 0; n < NX; ++n) {
        const int off = n < NX - 1 ? n : NX - 2;
        const double x = -1.0 + 2.0 * (double)n / 511.0;
        double N[4] = {1.0, 0.0, 0.0, 0.0};
        for (int d = 1; d <= 3; ++d) {
            double saved = 0.0;
            for (int r = 0; r < d; ++r) {
                const double tr = dknot(off + 3 + r + 1);
                const double tl = dknot(off + 3 + r + 1 - d);
                const double temp = N[r] / (tr - tl);
                N[r] = saved + (tr - x) * temp;
                saved = (x - tl) * temp;
            }
            N[d] = saved;
        }
        for (int r = 0; r < 4; ++r) bx[n][r] = N[r];
    }
    double A[M][4] = {};
    for (int i = 0; i < M; ++i) {
        double a0 = 1e-3, a1 = 0.0, a2 = 0.0, a3 = 0.0;
        const int nlo = i - 3 < 0 ? 0 : i - 3;
        const int nhi = i + 1 > NX - 1 ? NX - 1 : i + 1;
        for (int n = nlo; n <= nhi; ++n) {
            const int off = n < NX - 1 ? n : NX - 2;
            const int ri = i - off;
            if (ri < 0 || ri > 3) continue;
            const double bi = bx[n][ri];
            a0 += bi * bx[n][ri];
            if (ri >= 1) a1 += bi * bx[n][ri - 1];
            if (ri >= 2) a2 += bi * bx[n][ri - 2];
            if (ri >= 3) a3 += bi * bx[n][ri - 3];
        }
        A[i][0] = a0; A[i][1] = a1; A[i][2] = a2; A[i][3] = a3;
    }
    {
        double rd1 = 0.0, l1p = 0.0, l2p = 0.0, rd2 = 0.0, l1pp = 0.0, rd3 = 0.0;
        for (int i = 0; i < M; ++i) {
            const double l3 = A[i][3] * rd3;
            const double l2 = (A[i][2] - l3 * l1pp) * rd2;
            const double l1 = (A[i][1] - l3 * l2p - l2 * l1p) * rd1;
            const double s  = A[i][0] - l3 * l3 - l2 * l2 - l1 * l1;
            const double rd = 1.0 / csqrt(s);
            T.lb[i][0] = (float)rd; T.lb[i][1] = (float)l1;
            T.lb[i][2] = (float)l2; T.lb[i][3] = (float)l3;
            rd3 = rd2; rd2 = rd1; rd1 = rd;
            l1pp = l1p; l1p = l1; l2p = l2;
        }
    }
    for (int i = 0; i < M; ++i)
        for (int r = 0; r < 4; ++r) {
            const int n = i - r;
            T.w4[i][r] = (n >= 0 && n <= NX - 2) ? (float)bx[n][r] : 0.0f;
        }
    for (int q = 0; q < 4; ++q) T.we[q] = (float)bx[NX - 1][q];
    return T;
}

__constant__ Tables TBL = make_tables();

// interior (Toeplitz / converged) constants as compile-time immediates
constexpr Tables HT = make_tables();
constexpr float CW0 = HT.w4[256][0], CW1 = HT.w4[256][1], CW2 = HT.w4[256][2], CW3 = HT.w4[256][3];
constexpr float CRD = HT.lb[256][0], CL1 = HT.lb[256][1], CL2 = HT.lb[256][2], CL3 = HT.lb[256][3];
// rows i with 48 <= i and i+3 <= 465 use the constants (both passes)
constexpr int INT_LO = 48, INT_HI = 462;

// interval index of eval point n (single fp32 path everywhere)
__device__ __forceinline__ int offf(int n) {
    const float xe = -1.0f + 2.0f * (float)n / 8191.0f;
    int off = (int)((xe + 1.0f) * 255.5f);
    return off < 0 ? 0 : (off > NX - 2 ? NX - 2 : off);
}

__device__ __forceinline__ float knotf(int j) {
    int c = j - 3;
    c = c < 0 ? 0 : (c > NX - 1 ? NX - 1 : c);
    return -1.0f + 2.0f * (float)c / 511.0f;
}

__device__ __forceinline__ void deboor3(float x, int j, float N[4]) {
    N[0] = 1.0f; N[1] = 0.0f; N[2] = 0.0f; N[3] = 0.0f;
#pragma unroll
    for (int d = 1; d <= 3; ++d) {
        float saved = 0.0f;
#pragma unroll
        for (int r = 0; r < 3; ++r) {
            if (r < d) {
                const float tr = knotf(j + r + 1);
                const float tl = knotf(j + r + 1 - d);
                const float temp = N[r] / (tr - tl);
                N[r] = saved + (tr - x) * temp;
                saved = (x - tl) * temp;
            }
        }
        N[d] = saved;
    }
}

__device__ __forceinline__ float zl(const float* __restrict__ Zr, int j) {
    j = j < 0 ? 0 : (j > NX - 1 ? NX - 1 : j);   // clamped; OOR taps have zero weight
    return Zr[j];
}

// ---------------------------------------------------------------------------
// Kernel 1: fused Btz + forward + backward substitution. Lane = one RHS.
// Z streamed global->register ring (depth 16); y window in lane-private LDS;
// interior rows use compile-time constant stencil (no memory); coef written
// transposed coefT[bc][i].
// ---------------------------------------------------------------------------
__global__ __launch_bounds__(256) void solve_fused(const float* __restrict__ Z,
                                                   float* __restrict__ coefT) {
    __shared__ float Ys[256 * YST];
    const int tid = threadIdx.x;
    const int b = blockIdx.x;

    // segment geometry (wave-uniform)
    const int nf = b * PPB;
    const int own_lo = offf(nf);
    const int own_hi = (b == NBLK - 1) ? M - 1 : offf(nf + PPB) - 1;
    const int r_hi = offf(nf + PPB - 1) + 3;
    int i0 = own_lo - WARM; i0 = i0 < 0 ? 0 : i0;
    int i_end = r_hi + WARM; i_end = i_end > M - 1 ? M - 1 : i_end;
    const int NR = i_end - i0 + 1;            // <= 84
    const int NRb = i_end - own_lo + 1;       // <= 52 (< YST)

    const float* Zr = Z + tid * NX;
    const int yoff = tid * YST;
    const float z511 = Zr[NX - 1];

    // prime window + depth-16 ring
    float zm1 = zl(Zr, i0 - 1), zm2 = zl(Zr, i0 - 2), zm3 = zl(Zr, i0 - 3);
    float rA[8], rB[8];
#pragma unroll
    for (int k = 0; k < 8; ++k) { rA[k] = zl(Zr, i0 + k); rB[k] = zl(Zr, i0 + 8 + k); }

    float y1 = 0.f, y2 = 0.f, y3 = 0.f;

#define FWD8(RB, IBASE)                                                          \
    {                                                                            \
        const int ib_ = (IBASE);                                                 \
        if (ib_ >= INT_LO && ib_ + 7 <= INT_HI) {                                \
            _Pragma("unroll")                                                    \
            for (int k = 0; k < 8; ++k) {                                        \
                const int i = ib_ + k;                                           \
                const float zn = RB[k];                                          \
                const float btz = CW0 * zn + CW1 * zm1 + CW2 * zm2 + CW3 * zm3;  \
                const float y = (btz - CL1 * y1 - CL2 * y2 - CL3 * y3) * CRD;    \
                if (i >= own_lo && i <= i_end) Ys[yoff + (i - own_lo)] = y;      \
                y3 = y2; y2 = y1; y1 = y;                                        \
                zm3 = zm2; zm2 = zm1; zm1 = zn;                                  \
                RB[k] = zl(Zr, i + 16);                                          \
            }                                                                    \
        } else {                                                                 \
            _Pragma("unroll")                                                    \
            for (int k = 0; k < 8; ++k) {                                        \
                const int i = ib_ + k;                                           \
                const int it = i < M ? i : M - 1;                                \
                const float4 w = *(const float4*)TBL.w4[it];                     \
                const float4 l = *(const float4*)TBL.lb[it];                     \
                const float zn = RB[k];                                          \
                float btz = w.x * zn + w.y * zm1 + w.z * zm2 + w.w * zm3;        \
                const int q = it - 510;                                          \
                if (q >= 0) btz += TBL.we[q] * z511;                             \
                const float y = (btz - l.y * y1 - l.z * y2 - l.w * y3) * l.x;    \
                if (i >= own_lo && i <= i_end) Ys[yoff + (i - own_lo)] = y;      \
                y3 = y2; y2 = y1; y1 = y;                                        \
                zm3 = zm2; zm2 = zm1; zm1 = zn;                                  \
                RB[k] = zl(Zr, i + 16);                                          \
            }                                                                    \
        }                                                                        \
    }

    const int nch = (NR + 15) >> 4;
    for (int cc = 0; cc < nch; ++cc) {
        const int ib = i0 + (cc << 4);
        FWD8(rA, ib)
        FWD8(rB, ib + 8)
    }
#undef FWD8

    // ---- backward: c_i = (y_i - lb[i+1].l1*c1 - lb[i+2].l2*c2 - lb[i+3].l3*c3)*lb[i].rd
    float* crow = coefT + (size_t)tid * M;
    float c1 = 0.f, c2 = 0.f, c3 = 0.f;
    const int topslot = i_end - own_lo;
    const int nbk = (NRb + 7) >> 3;
    for (int cc = 0; cc < nbk; ++cc) {
        const int ib = i_end - (cc << 3);     // top row of this chunk
        float zb[8];
#pragma unroll
        for (int k = 0; k < 8; ++k) {
            int s = topslot - (cc << 3) - k;
            zb[k] = Ys[yoff + (s < 0 ? 0 : s)];
        }
        if (ib - 7 >= INT_LO && ib <= INT_HI) {
#pragma unroll
            for (int k = 0; k < 8; ++k) {
                const int i = ib - k;
                const float c = (zb[k] - CL1 * c1 - CL2 * c2 - CL3 * c3) * CRD;
                if (i >= own_lo && i <= own_hi) crow[i] = c;
                c3 = c2; c2 = c1; c1 = c;
            }
        } else {
#pragma unroll
            for (int k = 0; k < 8; ++k) {
                const int i = ib - k;
                const int it = i < 0 ? 0 : i;
                const float rd = TBL.lb[it][0];
                const float e1 = TBL.lb[it + 1][1];
                const float e2 = TBL.lb[it + 2][2];
                const float e3 = TBL.lb[it + 3][3];
                const float c = (zb[k] - e1 * c1 - e2 * c2 - e3 * c3) * rd;
                if (i >= own_lo && i <= own_hi) crow[i] = c;
                c3 = c2; c2 = c1; c1 = c;
            }
        }
    }
}

// ---------------------------------------------------------------------------
// Kernel 2: evaluate. 4 points/thread, float4 stores; coefT reads are
// wave-broadcast (same bc per wave, overlapping off windows).
// ---------------------------------------------------------------------------
__device__ __forceinline__ float evalpt(const float* __restrict__ cr, int n) {
    const float xe = -1.0f + 2.0f * (float)n / 8191.0f;
    int off = (int)((xe + 1.0f) * 255.5f);
    off = off < 0 ? 0 : (off > NX - 2 ? NX - 2 : off);
    float N[4];
    deboor3(xe, off + 3, N);
    return N[0] * cr[off] + N[1] * cr[off + 1] + N[2] * cr[off + 2] + N[3] * cr[off + 3];
}

__global__ __launch_bounds__(256) void eval_kernel(const float* __restrict__ coefT,
                                                   float* __restrict__ out) {
    const int bc = blockIdx.x >> 3;                       // 0..255
    const int n0q = ((blockIdx.x & 7) << 10) | (threadIdx.x << 2);
    const float* cr = coefT + (size_t)bc * M;
    float4 r;
    r.x = evalpt(cr, n0q + 0);
    r.y = evalpt(cr, n0q + 1);
    r.z = evalpt(cr, n0q + 2);
    r.w = evalpt(cr, n0q + 3);
    *(float4*)(out + (size_t)bc * NE + n0q) = r;
}

}  // namespace

extern "C" void kernel_launch(void* const* d_in, const int* in_sizes, int n_in,
                              void* d_out, int out_size, void* d_ws, size_t ws_size,
                              hipStream_t stream) {
    const float* Z = (const float*)d_in[0];
    float* out = (float*)d_out;
    float* coefT = (float*)d_ws;    // [NBC * M] floats, transposed coef

    hipLaunchKernelGGL(solve_fused, dim3(NBLK), dim3(256), 0, stream, Z, coefT);
    hipLaunchKernelGGL(eval_kernel, dim3(2048), dim3(256), 0, stream, coefT, out);
}

// Round 7
// 23.792 us; speedup vs baseline: 12.4200x; 1.5973x over previous
//
#include <hip/hip_runtime.h>
#include <math.h>

namespace {

constexpr int NX  = 512;    // data points
constexpr int M   = 514;    // basis functions
constexpr int NE  = 8192;   // eval points
constexpr int NBC = 256;    // batch*channels
constexpr int WARM = 32;    // warm-up rows (decay ~0.268^32 -> fp32-exact)

constexpr int NBLK = 256;   // one block per 32 eval points
constexpr int PPB  = NE / NBLK;     // 32
constexpr int SLOTS  = 76;  // LDS slots per bc row (cols then rows, in place)
constexpr int STRIDE = 77;  // odd -> conflict-free

// ---------------------------------------------------------------------------
// Compile-time tables: basis weights and banded Cholesky factor (double math).
// ---------------------------------------------------------------------------
constexpr double dknot(int j) {
    int c = j - 3;
    c = c < 0 ? 0 : (c > NX - 1 ? NX - 1 : c);
    return -1.0 + 2.0 * (double)c / 511.0;
}

constexpr double csqrt(double x) {
    double r = x > 1.0 ? x : 1.0;
    for (int k = 0; k < 50; ++k) r = 0.5 * (r + x / r);
    return r;
}

struct Tables {
    alignas(16) float lb[M + 3][4];  // rd=1/diag, l1, l2, l3 (3 zero pad rows)
    alignas(16) float w4[M][4];      // w4[i][r] = weight of Z[i-r] in Btz[i] (0 if OOR)
    float we[4];                     // weight of Z[511] in Btz[510+q]
};

constexpr Tables make_tables() {
    Tables T{};
    double bx[NX][4] = {};
    for (int n = 0; n < NX; ++n) {
        const int off = n < NX - 1 ? n : NX - 2;
        const double x = -1.0 + 2.0 * (double)n / 511.0;
        double N[4] = {1.0, 0.0, 0.0, 0.0};
        for (int d = 1; d <= 3; ++d) {
            double saved = 0.0;
            for (int r = 0; r < d; ++r) {
                const double tr = dknot(off + 3 + r + 1);
                const double tl = dknot(off + 3 + r + 1 - d);
                const double temp = N[r] / (tr - tl);
                N[r] = saved + (tr - x) * temp;
                saved = (x - tl) * temp;
            }
            N[d] = saved;
        }
        for (int r = 0; r < 4; ++r) bx[n][r] = N[r];
    }
    double A[M][4] = {};
    for (int i = 0; i < M; ++i) {
        double a0 = 1e-3, a1 = 0.0, a2 = 0.0, a3 = 0.0;
        const int nlo = i - 3 < 0 ? 0 : i - 3;
        const int nhi = i + 1 > NX - 1 ? NX - 1 : i + 1;
        for (int n = nlo; n <= nhi; ++n) {
            const int off = n < NX - 1 ? n : NX - 2;
            const int ri = i - off;
            if (ri < 0 || ri > 3) continue;
            const double bi = bx[n][ri];
            a0 += bi * bx[n][ri];
            if (ri >= 1) a1 += bi * bx[n][ri - 1];
            if (ri >= 2) a2 += bi * bx[n][ri - 2];
            if (ri >= 3) a3 += bi * bx[n][ri - 3];
        }
        A[i][0] = a0; A[i][1] = a1; A[i][2] = a2; A[i][3] = a3;
    }
    {
        double rd1 = 0.0, l1p = 0.0, l2p = 0.0, rd2 = 0.0, l1pp = 0.0, rd3 = 0.0;
        for (int i = 0; i < M; ++i) {
            const double l3 = A[i][3] * rd3;
            const double l2 = (A[i][2] - l3 * l1pp) * rd2;
            const double l1 = (A[i][1] - l3 * l2p - l2 * l1p) * rd1;
            const double s  = A[i][0] - l3 * l3 - l2 * l2 - l1 * l1;
            const double rd = 1.0 / csqrt(s);
            T.lb[i][0] = (float)rd; T.lb[i][1] = (float)l1;
            T.lb[i][2] = (float)l2; T.lb[i][3] = (float)l3;
            rd3 = rd2; rd2 = rd1; rd1 = rd;
            l1pp = l1p; l1p = l1; l2p = l2;
        }
    }
    for (int i = 0; i < M; ++i)
        for (int r = 0; r < 4; ++r) {
            const int n = i - r;
            T.w4[i][r] = (n >= 0 && n <= NX - 2) ? (float)bx[n][r] : 0.0f;
        }
    for (int q = 0; q < 4; ++q) T.we[q] = (float)bx[NX - 1][q];
    return T;
}

__constant__ Tables TBL = make_tables();

// interior (Toeplitz / converged) constants as compile-time immediates
constexpr Tables HT = make_tables();
constexpr float CW0 = HT.w4[256][0], CW1 = HT.w4[256][1], CW2 = HT.w4[256][2], CW3 = HT.w4[256][3];
constexpr float CRD = HT.lb[256][0], CL1 = HT.lb[256][1], CL2 = HT.lb[256][2], CL3 = HT.lb[256][3];
constexpr int INT_LO = 48, INT_HI = 462;

// interval index of eval point n (single fp32 path everywhere)
__device__ __forceinline__ int offf(int n) {
    const float xe = -1.0f + 2.0f * (float)n / 8191.0f;
    int off = (int)((xe + 1.0f) * 255.5f);
    return off < 0 ? 0 : (off > NX - 2 ? NX - 2 : off);
}

__device__ __forceinline__ float knotf(int j) {
    int c = j - 3;
    c = c < 0 ? 0 : (c > NX - 1 ? NX - 1 : c);
    return -1.0f + 2.0f * (float)c / 511.0f;
}

__device__ __forceinline__ void deboor3(float x, int j, float N[4]) {
    N[0] = 1.0f; N[1] = 0.0f; N[2] = 0.0f; N[3] = 0.0f;
#pragma unroll
    for (int d = 1; d <= 3; ++d) {
        float saved = 0.0f;
#pragma unroll
        for (int r = 0; r < 3; ++r) {
            if (r < d) {
                const float tr = knotf(j + r + 1);
                const float tl = knotf(j + r + 1 - d);
                const float temp = N[r] / (tr - tl);
                N[r] = saved + (tr - x) * temp;
                saved = (x - tl) * temp;
            }
        }
        N[d] = saved;
    }
}

// ---------------------------------------------------------------------------
// Single fused kernel. Block b handles eval points [b*32, b*32+32) x all 256
// bc. Stages the needed Z window (coalesced, A/B pipelined) into LDS rows
// (one row per bc, stride 77), runs warm-up fwd+bwd banded substitution
// per-lane entirely in LDS (slot i-i0 holds col i-3 -> y_i -> coef_i as data
// dies), then evaluates directly from LDS coef. No global intermediates.
// ---------------------------------------------------------------------------
__global__ __launch_bounds__(256) void spline_fused(const float* __restrict__ Z,
                                                    float* __restrict__ out) {
    __shared__ float Bs[NBC * STRIDE];   // 78.8 KB
    const int tid = threadIdx.x;
    const int b = blockIdx.x;
    const int ns = b * PPB;

    // wave-uniform geometry
    const int e_lo = offf(ns);                    // first coef row eval needs
    const int e_hi = offf(ns + PPB - 1) + 3;      // last coef row eval needs
    int i0 = e_lo - WARM;  i0 = i0 < 0 ? 0 : i0;  // forward start (exact if 0)
    int i_end = e_hi + WARM;  i_end = i_end > M - 1 ? M - 1 : i_end;
    const int n0 = i0 - 3;                        // first staged Z column
    const int NRr = i_end - i0 + 1;               // forward rows  (<= 70)
    const int NRb = i_end - e_lo + 1;             // backward rows (<= 38)

    // ---- stage Z[bc][n0 .. n0+SLOTS) -> Bs[bc][slot], coalesced ----
    const int wid = tid >> 6, lane = tid & 63;
    {
        int ja = n0 + lane;
        ja = ja < 0 ? 0 : (ja > NX - 1 ? NX - 1 : ja);     // clamped: OOR taps have zero weight
        int jb = n0 + 64 + lane;
        jb = jb < 0 ? 0 : (jb > NX - 1 ? NX - 1 : jb);
        const bool bon = (64 + lane) < SLOTS;              // lanes 0..11 do chunk 2

#define LOADG(p, kk)                                                       \
        { const float* zp = Z + (size_t)((wid << 6) + (kk)) * NX;          \
          p##0 = zp[ja];          p##1 = zp[NX + ja];                      \
          p##2 = zp[2 * NX + ja]; p##3 = zp[3 * NX + ja];                  \
          if (bon) { p##4 = zp[jb];          p##5 = zp[NX + jb];           \
                     p##6 = zp[2 * NX + jb]; p##7 = zp[3 * NX + jb]; } }
#define WRITEG(p, kk)                                                      \
        { float* wp = Bs + ((wid << 6) + (kk)) * STRIDE;                   \
          wp[lane] = p##0;              wp[STRIDE + lane] = p##1;          \
          wp[2 * STRIDE + lane] = p##2; wp[3 * STRIDE + lane] = p##3;      \
          if (bon) { wp[64 + lane] = p##4;                                 \
                     wp[STRIDE + 64 + lane] = p##5;                        \
                     wp[2 * STRIDE + 64 + lane] = p##6;                    \
                     wp[3 * STRIDE + 64 + lane] = p##7; } }

        float A0, A1, A2, A3, A4, A5, A6, A7;
        float Q0, Q1, Q2, Q3, Q4, Q5, Q6, Q7;
        LOADG(A, 0)
#pragma unroll
        for (int k = 0; k < 64; k += 8) {
            LOADG(Q, k + 4)
            WRITEG(A, k)
            if (k + 8 < 64) LOADG(A, k + 8)
            WRITEG(Q, k + 4)
        }
#undef LOADG
#undef WRITEG
    }
    __syncthreads();

    // ---- forward substitution (lane = bc), in place in Bs ----
    const int bc = tid;
    float* Brow = Bs + bc * STRIDE;
    const int s511 = 514 - i0;    // slot of Z col 511 (never overwritten: row slot would be 514)
    const float z511 = (s511 >= 0 && s511 < SLOTS) ? Brow[s511] : 0.0f;

    float y1 = 0.f, y2 = 0.f, y3 = 0.f;
    const int nfb = (NRr + 7) >> 3;
    for (int cc = 0; cc < nfb; ++cc) {
        const int ri = cc << 3;
        const int ib = i0 + ri;
        float zb[11];
#pragma unroll
        for (int m = 0; m < 11; ++m) zb[m] = Brow[ri + m];   // ri+10 <= 74 < SLOTS
        if (ib >= INT_LO && ib + 7 <= INT_HI) {
#pragma unroll
            for (int k = 0; k < 8; ++k) {
                const float btz = CW0 * zb[k + 3] + CW1 * zb[k + 2] + CW2 * zb[k + 1] + CW3 * zb[k];
                const float y = (btz - CL1 * y1 - CL2 * y2 - CL3 * y3) * CRD;
                if (ri + k < NRr) Brow[ri + k] = y;
                y3 = y2; y2 = y1; y1 = y;
            }
        } else {
#pragma unroll
            for (int k = 0; k < 8; ++k) {
                const int i = ib + k;
                const int it = i < M ? i : M - 1;
                const float4 w = *(const float4*)TBL.w4[it];
                const float4 l = *(const float4*)TBL.lb[it];
                float btz = w.x * zb[k + 3] + w.y * zb[k + 2] + w.z * zb[k + 1] + w.w * zb[k];
                const int q = it - 510;
                if (q >= 0) btz += TBL.we[q] * z511;
                const float y = (btz - l.y * y1 - l.z * y2 - l.w * y3) * l.x;
                if (ri + k < NRr) Brow[ri + k] = y;
                y3 = y2; y2 = y1; y1 = y;
            }
        }
    }

    // ---- backward substitution, coef overwrites y in place ----
    const int top = i_end - i0;
    float c1 = 0.f, c2 = 0.f, c3 = 0.f;
    const int nbb = (NRb + 7) >> 3;
    for (int cc = 0; cc < nbb; ++cc) {
        const int ib = i_end - (cc << 3);
        float zb[8];
#pragma unroll
        for (int k = 0; k < 8; ++k) {
            int s = top - (cc << 3) - k;
            zb[k] = Brow[s < 0 ? 0 : s];
        }
        if (ib - 7 >= INT_LO && ib <= INT_HI) {
#pragma unroll
            for (int k = 0; k < 8; ++k) {
                const int i = ib - k;
                const float c = (zb[k] - CL1 * c1 - CL2 * c2 - CL3 * c3) * CRD;
                if ((cc << 3) + k < NRb) Brow[i - i0] = c;
                c3 = c2; c2 = c1; c1 = c;
            }
        } else {
#pragma unroll
            for (int k = 0; k < 8; ++k) {
                const int i = ib - k;
                const int it = i < 0 ? 0 : i;
                const float rd = TBL.lb[it][0];
                const float e1 = TBL.lb[it + 1][1];
                const float e2 = TBL.lb[it + 2][2];
                const float e3 = TBL.lb[it + 3][3];
                const float c = (zb[k] - e1 * c1 - e2 * c2 - e3 * c3) * rd;
                if ((cc << 3) + k < NRb) Brow[i - i0] = c;
                c3 = c2; c2 = c1; c1 = c;
            }
        }
    }
    __syncthreads();

    // ---- evaluate 32 points x 256 bc from LDS coef ----
    const int p = tid & 31;        // point within slice
    const int g = tid >> 5;        // bc group 0..7
    const int n = ns + p;
    const float xe = -1.0f + 2.0f * (float)n / 8191.0f;
    int off = (int)((xe + 1.0f) * 255.5f);
    off = off < 0 ? 0 : (off > NX - 2 ? NX - 2 : off);
    float N[4];
    deboor3(xe, off + 3, N);
    const int so = off - i0;       // slot of coef row `off` (>= e_lo - i0 >= 0)
#pragma unroll 4
    for (int it = 0; it < 32; ++it) {
        const int bcw = (g << 5) + it;
        const float* Cr = Bs + bcw * STRIDE + so;
        out[(size_t)bcw * NE + n] =
            N[0] * Cr[0] + N[1] * Cr[1] + N[2] * Cr[2] + N[3] * Cr[3];
    }
}

}  // namespace

extern "C" void kernel_launch(void* const* d_in, const int* in_sizes, int n_in,
                              void* d_out, int out_size, void* d_ws, size_t ws_size,
                              hipStream_t stream) {
    const float* Z = (const float*)d_in[0];
    float* out = (float*)d_out;
    (void)d_ws; (void)ws_size;

    hipLaunchKernelGGL(spline_fused, dim3(NBLK), dim3(256), 0, stream, Z, out);
}

// Round 8
// 21.959 us; speedup vs baseline: 13.4565x; 1.0835x over previous
//
#include <hip/hip_runtime.h>
#include <math.h>

namespace {

constexpr int NX  = 512;    // data points
constexpr int M   = 514;    // basis functions
constexpr int NE  = 8192;   // eval points
constexpr int NBC = 256;    // batch*channels
constexpr int WARM = 24;    // warm-up rows (error ~ t*0.268^t ~ 5e-13 -> fp32-exact)

constexpr int NBLK = 512;   // one block per 16 eval points -> 2 blocks/CU
constexpr int PPB  = NE / NBLK;     // 16
constexpr int SLOTS  = 56;  // staged Z columns per bc row (>= NRr+3 = 56)
constexpr int STRIDE = 59;  // odd (conflict-free); >= 59 so fwd over-reads stay in-row

// ---------------------------------------------------------------------------
// Compile-time tables: basis weights and banded Cholesky factor (double math).
// ---------------------------------------------------------------------------
constexpr double dknot(int j) {
    int c = j - 3;
    c = c < 0 ? 0 : (c > NX - 1 ? NX - 1 : c);
    return -1.0 + 2.0 * (double)c / 511.0;
}

constexpr double csqrt(double x) {
    double r = x > 1.0 ? x : 1.0;
    for (int k = 0; k < 50; ++k) r = 0.5 * (r + x / r);
    return r;
}

struct Tables {
    alignas(16) float lb[M + 3][4];  // rd=1/diag, l1, l2, l3 (3 zero pad rows)
    alignas(16) float w4[M][4];      // w4[i][r] = weight of Z[i-r] in Btz[i] (0 if OOR)
    float we[4];                     // weight of Z[511] in Btz[510+q]
};

constexpr Tables make_tables() {
    Tables T{};
    double bx[NX][4] = {};
    for (int n = 0; n < NX; ++n) {
        const int off = n < NX - 1 ? n : NX - 2;
        const double x = -1.0 + 2.0 * (double)n / 511.0;
        double N[4] = {1.0, 0.0, 0.0, 0.0};
        for (int d = 1; d <= 3; ++d) {
            double saved = 0.0;
            for (int r = 0; r < d; ++r) {
                const double tr = dknot(off + 3 + r + 1);
                const double tl = dknot(off + 3 + r + 1 - d);
                const double temp = N[r] / (tr - tl);
                N[r] = saved + (tr - x) * temp;
                saved = (x - tl) * temp;
            }
            N[d] = saved;
        }
        for (int r = 0; r < 4; ++r) bx[n][r] = N[r];
    }
    double A[M][4] = {};
    for (int i = 0; i < M; ++i) {
        double a0 = 1e-3, a1 = 0.0, a2 = 0.0, a3 = 0.0;
        const int nlo = i - 3 < 0 ? 0 : i - 3;
        const int nhi = i + 1 > NX - 1 ? NX - 1 : i + 1;
        for (int n = nlo; n <= nhi; ++n) {
            const int off = n < NX - 1 ? n : NX - 2;
            const int ri = i - off;
            if (ri < 0 || ri > 3) continue;
            const double bi = bx[n][ri];
            a0 += bi * bx[n][ri];
            if (ri >= 1) a1 += bi * bx[n][ri - 1];
            if (ri >= 2) a2 += bi * bx[n][ri - 2];
            if (ri >= 3) a3 += bi * bx[n][ri - 3];
        }
        A[i][0] = a0; A[i][1] = a1; A[i][2] = a2; A[i][3] = a3;
    }
    {
        double rd1 = 0.0, l1p = 0.0, l2p = 0.0, rd2 = 0.0, l1pp = 0.0, rd3 = 0.0;
        for (int i = 0; i < M; ++i) {
            const double l3 = A[i][3] * rd3;
            const double l2 = (A[i][2] - l3 * l1pp) * rd2;
            const double l1 = (A[i][1] - l3 * l2p - l2 * l1p) * rd1;
            const double s  = A[i][0] - l3 * l3 - l2 * l2 - l1 * l1;
            const double rd = 1.0 / csqrt(s);
            T.lb[i][0] = (float)rd; T.lb[i][1] = (float)l1;
            T.lb[i][2] = (float)l2; T.lb[i][3] = (float)l3;
            rd3 = rd2; rd2 = rd1; rd1 = rd;
            l1pp = l1p; l1p = l1; l2p = l2;
        }
    }
    for (int i = 0; i < M; ++i)
        for (int r = 0; r < 4; ++r) {
            const int n = i - r;
            T.w4[i][r] = (n >= 0 && n <= NX - 2) ? (float)bx[n][r] : 0.0f;
        }
    for (int q = 0; q < 4; ++q) T.we[q] = (float)bx[NX - 1][q];
    return T;
}

__constant__ Tables TBL = make_tables();

// interior (Toeplitz / converged) constants as compile-time immediates
constexpr Tables HT = make_tables();
constexpr float CW0 = HT.w4[256][0], CW1 = HT.w4[256][1], CW2 = HT.w4[256][2], CW3 = HT.w4[256][3];
constexpr float CRD = HT.lb[256][0], CL1 = HT.lb[256][1], CL2 = HT.lb[256][2], CL3 = HT.lb[256][3];
constexpr int INT_LO = 48, INT_HI = 462;

// interval index of eval point n (single fp32 path everywhere)
__device__ __forceinline__ int offf(int n) {
    const float xe = -1.0f + 2.0f * (float)n / 8191.0f;
    int off = (int)((xe + 1.0f) * 255.5f);
    return off < 0 ? 0 : (off > NX - 2 ? NX - 2 : off);
}

__device__ __forceinline__ float knotf(int j) {
    int c = j - 3;
    c = c < 0 ? 0 : (c > NX - 1 ? NX - 1 : c);
    return -1.0f + 2.0f * (float)c / 511.0f;
}

__device__ __forceinline__ void deboor3(float x, int j, float N[4]) {
    N[0] = 1.0f; N[1] = 0.0f; N[2] = 0.0f; N[3] = 0.0f;
#pragma unroll
    for (int d = 1; d <= 3; ++d) {
        float saved = 0.0f;
#pragma unroll
        for (int r = 0; r < 3; ++r) {
            if (r < d) {
                const float tr = knotf(j + r + 1);
                const float tl = knotf(j + r + 1 - d);
                const float temp = N[r] / (tr - tl);
                N[r] = saved + (tr - x) * temp;
                saved = (x - tl) * temp;
            }
        }
        N[d] = saved;
    }
}

// ---------------------------------------------------------------------------
// Single fused kernel. Block b handles eval points [b*16, b*16+16) x all 256
// bc. Stage the Z window (coalesced, pipelined) into LDS (row per bc,
// stride 59), run warm-up fwd+bwd banded substitution per-lane in LDS
// (slot i-i0: Z col i-3 -> y_i -> coef_i as data dies), then evaluate from
// LDS coef with float4 stores. 60.4 KB LDS -> 2 blocks/CU, 8 waves/CU.
// ---------------------------------------------------------------------------
__global__ __launch_bounds__(256) void spline_fused(const float* __restrict__ Z,
                                                    float* __restrict__ out) {
    __shared__ float Bs[NBC * STRIDE];   // 60.4 KB
    const int tid = threadIdx.x;
    const int b = blockIdx.x;
    const int ns = b * PPB;

    // wave-uniform geometry
    const int e_lo = offf(ns);                    // first coef row eval needs
    const int e_hi = offf(ns + PPB - 1) + 3;      // last coef row eval needs
    int i0 = e_lo - WARM;  i0 = i0 < 0 ? 0 : i0;  // forward start (exact if 0)
    int i_end = e_hi + WARM;  i_end = i_end > M - 1 ? M - 1 : i_end;
    const int n0 = i0 - 3;                        // first staged Z column
    const int NRr = i_end - i0 + 1;               // forward rows  (<= 53)
    const int NRb = i_end - e_lo + 1;             // backward rows (<= 29)

    // ---- stage Z[bc][n0 .. n0+SLOTS) -> Bs[bc][slot], coalesced, pipelined --
    const int wid = tid >> 6, lane = tid & 63;
    {
        int ja = n0 + lane;
        ja = ja < 0 ? 0 : (ja > NX - 1 ? NX - 1 : ja);   // OOR taps have zero weight
        const bool on = lane < SLOTS;

#define LOADG(p, kk)                                                       \
        { const float* zp = Z + (size_t)((wid << 6) + (kk)) * NX;          \
          if (on) { p##0 = zp[ja];          p##1 = zp[NX + ja];            \
                    p##2 = zp[2 * NX + ja]; p##3 = zp[3 * NX + ja]; } }
#define WRITEG(p, kk)                                                      \
        { float* wp = Bs + ((wid << 6) + (kk)) * STRIDE;                   \
          if (on) { wp[lane] = p##0;              wp[STRIDE + lane] = p##1; \
                    wp[2 * STRIDE + lane] = p##2; wp[3 * STRIDE + lane] = p##3; } }

        float A0, A1, A2, A3, Q0, Q1, Q2, Q3;
        LOADG(A, 0)
#pragma unroll
        for (int k = 0; k < 64; k += 8) {
            LOADG(Q, k + 4)
            WRITEG(A, k)
            if (k + 8 < 64) LOADG(A, k + 8)
            WRITEG(Q, k + 4)
        }
#undef LOADG
#undef WRITEG
    }
    __syncthreads();

    // ---- forward substitution (lane = bc), in place in Bs ----
    const int bc = tid;
    float* Brow = Bs + bc * STRIDE;
    const int s511 = 514 - i0;    // slot of Z col 511 (read before overwrite)
    const float z511 = (s511 >= 0 && s511 < SLOTS) ? Brow[s511] : 0.0f;

    float y1 = 0.f, y2 = 0.f, y3 = 0.f;
    const int nfb = (NRr + 7) >> 3;
    for (int cc = 0; cc < nfb; ++cc) {
        const int ri = cc << 3;
        const int ib = i0 + ri;
        float zb[11];
#pragma unroll
        for (int m = 0; m < 11; ++m) zb[m] = Brow[ri + m];   // ri+10 <= 58 < STRIDE
        if (ib >= INT_LO && ib + 7 <= INT_HI) {
#pragma unroll
            for (int k = 0; k < 8; ++k) {
                const float btz = CW0 * zb[k + 3] + CW1 * zb[k + 2] + CW2 * zb[k + 1] + CW3 * zb[k];
                const float y = (btz - CL1 * y1 - CL2 * y2 - CL3 * y3) * CRD;
                if (ri + k < NRr) Brow[ri + k] = y;
                y3 = y2; y2 = y1; y1 = y;
            }
        } else {
#pragma unroll
            for (int k = 0; k < 8; ++k) {
                const int i = ib + k;
                const int it = i < M ? i : M - 1;
                const float4 w = *(const float4*)TBL.w4[it];
                const float4 l = *(const float4*)TBL.lb[it];
                float btz = w.x * zb[k + 3] + w.y * zb[k + 2] + w.z * zb[k + 1] + w.w * zb[k];
                const int q = it - 510;
                if (q >= 0) btz += TBL.we[q] * z511;
                const float y = (btz - l.y * y1 - l.z * y2 - l.w * y3) * l.x;
                if (ri + k < NRr) Brow[ri + k] = y;
                y3 = y2; y2 = y1; y1 = y;
            }
        }
    }

    // ---- backward substitution, coef overwrites y in place ----
    const int top = i_end - i0;
    float c1 = 0.f, c2 = 0.f, c3 = 0.f;
    const int nbb = (NRb + 7) >> 3;
    for (int cc = 0; cc < nbb; ++cc) {
        const int ib = i_end - (cc << 3);
        float zb[8];
#pragma unroll
        for (int k = 0; k < 8; ++k) {
            int s = top - (cc << 3) - k;
            zb[k] = Brow[s < 0 ? 0 : s];
        }
        if (ib - 7 >= INT_LO && ib <= INT_HI) {
#pragma unroll
            for (int k = 0; k < 8; ++k) {
                const int i = ib - k;
                const float c = (zb[k] - CL1 * c1 - CL2 * c2 - CL3 * c3) * CRD;
                if ((cc << 3) + k < NRb) Brow[i - i0] = c;
                c3 = c2; c2 = c1; c1 = c;
            }
        } else {
#pragma unroll
            for (int k = 0; k < 8; ++k) {
                const int i = ib - k;
                const int it = i < 0 ? 0 : i;
                const float rd = TBL.lb[it][0];
                const float e1 = TBL.lb[it + 1][1];
                const float e2 = TBL.lb[it + 2][2];
                const float e3 = TBL.lb[it + 3][3];
                const float c = (zb[k] - e1 * c1 - e2 * c2 - e3 * c3) * rd;
                if ((cc << 3) + k < NRb) Brow[i - i0] = c;
                c3 = c2; c2 = c1; c1 = c;
            }
        }
    }
    __syncthreads();

    // ---- evaluate 16 points x 256 bc from LDS coef, float4 stores ----
    const int q  = tid & 3;        // quad of 4 points
    const int bc0 = tid >> 2;      // 0..63
    float Nv[4][4];
    int so[4];
#pragma unroll
    for (int j = 0; j < 4; ++j) {
        const int n = ns + (q << 2) + j;
        const float xe = -1.0f + 2.0f * (float)n / 8191.0f;
        int off = (int)((xe + 1.0f) * 255.5f);
        off = off < 0 ? 0 : (off > NX - 2 ? NX - 2 : off);
        deboor3(xe, off + 3, Nv[j]);
        so[j] = off - i0;          // >= e_lo - i0 >= 0
    }
#pragma unroll
    for (int it = 0; it < 4; ++it) {
        const int bcw = bc0 + (it << 6);
        const float* Cr = Bs + bcw * STRIDE;
        float4 r;
        r.x = Nv[0][0] * Cr[so[0]] + Nv[0][1] * Cr[so[0] + 1] + Nv[0][2] * Cr[so[0] + 2] + Nv[0][3] * Cr[so[0] + 3];
        r.y = Nv[1][0] * Cr[so[1]] + Nv[1][1] * Cr[so[1] + 1] + Nv[1][2] * Cr[so[1] + 2] + Nv[1][3] * Cr[so[1] + 3];
        r.z = Nv[2][0] * Cr[so[2]] + Nv[2][1] * Cr[so[2] + 1] + Nv[2][2] * Cr[so[2] + 2] + Nv[2][3] * Cr[so[2] + 3];
        r.w = Nv[3][0] * Cr[so[3]] + Nv[3][1] * Cr[so[3] + 1] + Nv[3][2] * Cr[so[3] + 2] + Nv[3][3] * Cr[so[3] + 3];
        *(float4*)(out + (size_t)bcw * NE + ns + (q << 2)) = r;
    }
}

}  // namespace

extern "C" void kernel_launch(void* const* d_in, const int* in_sizes, int n_in,
                              void* d_out, int out_size, void* d_ws, size_t ws_size,
                              hipStream_t stream) {
    const float* Z = (const float*)d_in[0];
    float* out = (float*)d_out;
    (void)d_ws; (void)ws_size;

    hipLaunchKernelGGL(spline_fused, dim3(NBLK), dim3(256), 0, stream, Z, out);
}